// Round 1
// baseline (990.533 us; speedup 1.0000x reference)
//
#include <hip/hip_runtime.h>
#include <hip/hip_bf16.h>
#include <cstdint>
#include <cstddef>

// ---------------------------------------------------------------------------
// FarmerGAT: 2-layer GAT on MI355X.
// Pipeline per call:
//   detect/convert edge dtype -> CSR build (hist, scan, scatter)
//   GEMM1 -> al1 -> denom1 -> aggregate1(+bias+ELU)
//   GEMM2 -> al2 -> denom2 -> aggregate2(+bias+ELU) -> d_out
// ---------------------------------------------------------------------------

static __device__ __forceinline__ float lrelu02(float x) { return x > 0.f ? x : 0.2f * x; }
static __device__ __forceinline__ float eluf(float x)    { return x > 0.f ? x : __expf(x) - 1.f; }

// --- edge dtype detect: int64 little-endian with values < 2^31 has zero odd words
__global__ void detect_kernel(const int* __restrict__ ei, int* __restrict__ flag, int e) {
    if (blockIdx.x == 0 && threadIdx.x == 0) {
        int zeros = 0;
        int m = e < 64 ? e : 64;
        for (int i = 0; i < m; ++i) if (ei[2 * i + 1] == 0) ++zeros;
        *flag = (zeros >= (m / 2 + 1)) ? 1 : 0;
    }
}

__global__ void convert_kernel(const int* __restrict__ ei, const int* __restrict__ flag,
                               int* __restrict__ es, int n2e) {
    int i = blockIdx.x * blockDim.x + threadIdx.x;
    if (i < n2e) es[i] = (*flag) ? ei[2 * i] : ei[i];
}

// --- CSR build ---
__global__ void hist_kernel(const int* __restrict__ dst, int* __restrict__ deg, int e, int et) {
    int i = blockIdx.x * blockDim.x + threadIdx.x;
    if (i < et) {
        int d = (i < e) ? dst[i] : (i - e);   // self loops appended
        atomicAdd(&deg[d], 1);
    }
}

// single-block exclusive scan (wave-shuffle based), n up to ~millions ok
__global__ __launch_bounds__(1024) void scan_kernel(const int* __restrict__ deg,
                                                    int* __restrict__ rowptr, int n) {
    __shared__ int wsum[16];
    __shared__ int s_carry;
    int t = threadIdx.x, lane = t & 63, w = t >> 6;
    if (t == 0) s_carry = 0;
    __syncthreads();
    for (int base = 0; base < n; base += 1024) {
        int i = base + t;
        int v = (i < n) ? deg[i] : 0;
        int incl = v;
        #pragma unroll
        for (int d = 1; d < 64; d <<= 1) {
            int o = __shfl_up(incl, d);
            if (lane >= d) incl += o;
        }
        if (lane == 63) wsum[w] = incl;
        __syncthreads();
        if (w == 0 && lane < 16) {
            int s = wsum[lane];
            int si = s;
            #pragma unroll
            for (int d = 1; d < 16; d <<= 1) {
                int o = __shfl_up(si, d);
                if (lane >= d) si += o;
            }
            wsum[lane] = si - s;  // exclusive
        }
        __syncthreads();
        int excl = s_carry + wsum[w] + incl - v;
        if (i < n) rowptr[i] = excl;
        int tot = excl + v;
        __syncthreads();
        if (t == 1023) s_carry = tot;
        __syncthreads();
    }
    if (t == 0) rowptr[n] = s_carry;
}

__global__ void scatter_kernel(const int* __restrict__ dst, int* __restrict__ cursor,
                               int* __restrict__ eid, int e, int et) {
    int i = blockIdx.x * blockDim.x + threadIdx.x;
    if (i < et) {
        int d = (i < e) ? dst[i] : (i - e);
        int pos = atomicAdd(&cursor[d], 1);
        eid[pos] = i;
    }
}

// --- fp32 tiled GEMM: C[M,N] = A[M,K] * B[K,N]; N multiple of 64, K multiple of 16
__global__ __launch_bounds__(256) void gemm_kernel(const float* __restrict__ A,
                                                   const float* __restrict__ B,
                                                   float* __restrict__ C,
                                                   int M, int N, int K) {
    __shared__ float As[16][64];  // [k][m] transposed for b128 reads
    __shared__ float Bs[16][64];
    int t = threadIdx.x;
    int tx = t & 15, ty = t >> 4;
    int bm = blockIdx.y * 64;
    int bn = blockIdx.x * 64;
    float acc[4][4] = {};
    for (int k0 = 0; k0 < K; k0 += 16) {
        {
            int row = t >> 2;
            int kk = (t & 3) * 4;
            int gr = bm + row;
            float4 a4 = (gr < M) ? *(const float4*)(A + (size_t)gr * K + k0 + kk)
                                 : make_float4(0.f, 0.f, 0.f, 0.f);
            As[kk + 0][row] = a4.x; As[kk + 1][row] = a4.y;
            As[kk + 2][row] = a4.z; As[kk + 3][row] = a4.w;
        }
        {
            int kr = t >> 4;
            int cc = (t & 15) * 4;
            float4 b4 = *(const float4*)(B + (size_t)(k0 + kr) * N + bn + cc);
            *(float4*)&Bs[kr][cc] = b4;
        }
        __syncthreads();
        #pragma unroll
        for (int kk = 0; kk < 16; ++kk) {
            float4 a4 = *(const float4*)&As[kk][ty * 4];
            float4 b4 = *(const float4*)&Bs[kk][tx * 4];
            float a[4] = {a4.x, a4.y, a4.z, a4.w};
            float b[4] = {b4.x, b4.y, b4.z, b4.w};
            #pragma unroll
            for (int i = 0; i < 4; ++i)
                #pragma unroll
                for (int j = 0; j < 4; ++j)
                    acc[i][j] += a[i] * b[j];
        }
        __syncthreads();
    }
    #pragma unroll
    for (int i = 0; i < 4; ++i) {
        int gr = bm + ty * 4 + i;
        if (gr < M) {
            float4 v = make_float4(acc[i][0], acc[i][1], acc[i][2], acc[i][3]);
            *(float4*)(C + (size_t)gr * N + bn + tx * 4) = v;
        }
    }
}

// --- attention logits, layer1 (4 heads x 64 ch): one wave per node
__global__ __launch_bounds__(256) void al_head4_kernel(const float* __restrict__ h1,
                                                       const float* __restrict__ a_src,
                                                       const float* __restrict__ a_dst,
                                                       float* __restrict__ als,
                                                       float* __restrict__ ald, int n) {
    int node = blockIdx.x * 4 + (threadIdx.x >> 6);
    int lane = threadIdx.x & 63;
    if (node >= n) return;
    #pragma unroll
    for (int h = 0; h < 4; ++h) {
        float v = h1[(size_t)node * 256 + h * 64 + lane];
        float ps = v * a_src[h * 64 + lane];
        float pd = v * a_dst[h * 64 + lane];
        #pragma unroll
        for (int d = 32; d > 0; d >>= 1) {
            ps += __shfl_down(ps, d);
            pd += __shfl_down(pd, d);
        }
        if (lane == 0) {
            als[node * 4 + h] = ps;
            ald[node * 4 + h] = pd;
        }
    }
}

// --- attention logits, layer2 (1 head x 64 ch): one wave per node
__global__ __launch_bounds__(256) void al_head1_kernel(const float* __restrict__ h2,
                                                       const float* __restrict__ a_src,
                                                       const float* __restrict__ a_dst,
                                                       float* __restrict__ als,
                                                       float* __restrict__ ald, int n) {
    int node = blockIdx.x * 4 + (threadIdx.x >> 6);
    int lane = threadIdx.x & 63;
    if (node >= n) return;
    float v = h2[(size_t)node * 64 + lane];
    float ps = v * a_src[lane];
    float pd = v * a_dst[lane];
    #pragma unroll
    for (int d = 32; d > 0; d >>= 1) {
        ps += __shfl_down(ps, d);
        pd += __shfl_down(pd, d);
    }
    if (lane == 0) {
        als[node] = ps;
        ald[node] = pd;
    }
}

// --- softmax denominators (no max-subtraction; logits are O(±7), exp is safe)
__global__ void denom4_kernel(const int* __restrict__ src, const int* __restrict__ dst,
                              const float* __restrict__ als, const float* __restrict__ ald,
                              float* __restrict__ den, int e, int et) {
    int i = blockIdx.x * blockDim.x + threadIdx.x;
    if (i >= et) return;
    int s, d;
    if (i < e) { s = src[i]; d = dst[i]; } else { s = d = i - e; }
    float4 a = *(const float4*)(als + (size_t)s * 4);
    float4 b = *(const float4*)(ald + (size_t)d * 4);
    atomicAdd(&den[d * 4 + 0], __expf(lrelu02(a.x + b.x)));
    atomicAdd(&den[d * 4 + 1], __expf(lrelu02(a.y + b.y)));
    atomicAdd(&den[d * 4 + 2], __expf(lrelu02(a.z + b.z)));
    atomicAdd(&den[d * 4 + 3], __expf(lrelu02(a.w + b.w)));
}

__global__ void denom1h_kernel(const int* __restrict__ src, const int* __restrict__ dst,
                               const float* __restrict__ als, const float* __restrict__ ald,
                               float* __restrict__ den, int e, int et) {
    int i = blockIdx.x * blockDim.x + threadIdx.x;
    if (i >= et) return;
    int s, d;
    if (i < e) { s = src[i]; d = dst[i]; } else { s = d = i - e; }
    atomicAdd(&den[d], __expf(lrelu02(als[s] + ald[d])));
}

// --- layer1 aggregation: one block per dst node, 256 threads = 256 channels
__global__ __launch_bounds__(256) void agg1_kernel(const float* __restrict__ h1,
                                                   const int* __restrict__ src,
                                                   const int* __restrict__ eid,
                                                   const int* __restrict__ rowptr,
                                                   const float* __restrict__ als,
                                                   const float* __restrict__ ald,
                                                   const float* __restrict__ den,
                                                   const float* __restrict__ b1,
                                                   float* __restrict__ x2, int e, int n) {
    int node = blockIdx.x;
    int t = threadIdx.x;
    int h = t >> 6;
    float rd = 1.f / (den[node * 4 + h] + 1e-16f);
    float aldn = ald[node * 4 + h];
    int p0 = rowptr[node], p1 = rowptr[node + 1];
    float acc = 0.f;
    for (int p = p0; p < p1; ++p) {
        int id = eid[p];
        int s = (id < e) ? src[id] : (id - e);
        float alpha = __expf(lrelu02(als[s * 4 + h] + aldn)) * rd;
        acc += alpha * h1[(size_t)s * 256 + t];
    }
    float v = acc + b1[t];
    x2[(size_t)node * 256 + t] = eluf(v);
}

// --- layer2 aggregation: one block per dst node, 4 edge-slots x 64 channels
__global__ __launch_bounds__(256) void agg2_kernel(const float* __restrict__ h2,
                                                   const int* __restrict__ src,
                                                   const int* __restrict__ eid,
                                                   const int* __restrict__ rowptr,
                                                   const float* __restrict__ als,
                                                   const float* __restrict__ ald,
                                                   const float* __restrict__ den,
                                                   const float* __restrict__ b2,
                                                   float* __restrict__ out, int e, int n) {
    __shared__ float red[256];
    int node = blockIdx.x;
    int t = threadIdx.x;
    int c = t & 63, ei = t >> 6;
    float rd = 1.f / (den[node] + 1e-16f);
    float aldn = ald[node];
    int p0 = rowptr[node], p1 = rowptr[node + 1];
    float acc = 0.f;
    for (int p = p0 + ei; p < p1; p += 4) {
        int id = eid[p];
        int s = (id < e) ? src[id] : (id - e);
        float alpha = __expf(lrelu02(als[s] + aldn)) * rd;
        acc += alpha * h2[(size_t)s * 64 + c];
    }
    red[t] = acc;
    __syncthreads();
    if (ei == 0) {
        float v = red[c] + red[64 + c] + red[128 + c] + red[192 + c] + b2[c];
        out[(size_t)node * 64 + c] = eluf(v);
    }
}

extern "C" void kernel_launch(void* const* d_in, const int* in_sizes, int n_in,
                              void* d_out, int out_size, void* d_ws, size_t ws_size,
                              hipStream_t stream) {
    const float* x   = (const float*)d_in[0];
    const int*   ei  = (const int*)d_in[1];
    const float* W1  = (const float*)d_in[2];
    const float* as1 = (const float*)d_in[3];
    const float* ad1 = (const float*)d_in[4];
    const float* b1  = (const float*)d_in[5];
    const float* W2  = (const float*)d_in[6];
    const float* as2 = (const float*)d_in[7];
    const float* ad2 = (const float*)d_in[8];
    const float* b2  = (const float*)d_in[9];
    float* out = (float*)d_out;

    const int n  = in_sizes[0] / 128;  // 50000
    const int e  = in_sizes[1] / 2;    // 800000
    const int et = e + n;

    char* w = (char*)d_ws;
    size_t off = 0;
    auto take = [&](size_t bytes) -> void* {
        void* p = w + off;
        off = (off + bytes + 255) & ~(size_t)255;
        return p;
    };
    float* h1   = (float*)take((size_t)n * 256 * 4);
    float* x2   = (float*)take((size_t)n * 256 * 4);
    float* h2   = (float*)take((size_t)n * 64 * 4);
    float* al1s = (float*)take((size_t)n * 4 * 4);
    float* al1d = (float*)take((size_t)n * 4 * 4);
    float* den1 = (float*)take((size_t)n * 4 * 4);
    float* al2s = (float*)take((size_t)n * 4);
    float* al2d = (float*)take((size_t)n * 4);
    float* den2 = (float*)take((size_t)n * 4);
    int* deg    = (int*)take((size_t)(n + 1) * 4);
    int* rowptr = (int*)take((size_t)(n + 1) * 4);
    int* cursor = (int*)take((size_t)(n + 1) * 4);
    int* eid    = (int*)take((size_t)et * 4);
    int* es     = (int*)take((size_t)2 * e * 4);
    int* flag   = (int*)take(256);

    // edge dtype normalize
    detect_kernel<<<1, 64, 0, stream>>>(ei, flag, e);
    int n2e = 2 * e;
    convert_kernel<<<(n2e + 255) / 256, 256, 0, stream>>>(ei, flag, es, n2e);
    const int* srcA = es;
    const int* dstA = es + e;

    // zero accumulators
    hipMemsetAsync(deg, 0, (size_t)n * 4, stream);
    hipMemsetAsync(den1, 0, (size_t)n * 16, stream);
    hipMemsetAsync(den2, 0, (size_t)n * 4, stream);

    // CSR build (by dst), reused for both layers
    hist_kernel<<<(et + 255) / 256, 256, 0, stream>>>(dstA, deg, e, et);
    scan_kernel<<<1, 1024, 0, stream>>>(deg, rowptr, n);
    hipMemcpyAsync(cursor, rowptr, (size_t)n * 4, hipMemcpyDeviceToDevice, stream);
    scatter_kernel<<<(et + 255) / 256, 256, 0, stream>>>(dstA, cursor, eid, e, et);

    // ---- layer 1 ----
    gemm_kernel<<<dim3(256 / 64, (n + 63) / 64), 256, 0, stream>>>(x, W1, h1, n, 256, 128);
    al_head4_kernel<<<(n + 3) / 4, 256, 0, stream>>>(h1, as1, ad1, al1s, al1d, n);
    denom4_kernel<<<(et + 255) / 256, 256, 0, stream>>>(srcA, dstA, al1s, al1d, den1, e, et);
    agg1_kernel<<<n, 256, 0, stream>>>(h1, srcA, eid, rowptr, al1s, al1d, den1, b1, x2, e, n);

    // ---- layer 2 ----
    gemm_kernel<<<dim3(64 / 64, (n + 63) / 64), 256, 0, stream>>>(x2, W2, h2, n, 64, 256);
    al_head1_kernel<<<(n + 3) / 4, 256, 0, stream>>>(h2, as2, ad2, al2s, al2d, n);
    denom1h_kernel<<<(et + 255) / 256, 256, 0, stream>>>(srcA, dstA, al2s, al2d, den2, e, et);
    agg2_kernel<<<n, 256, 0, stream>>>(h2, srcA, eid, rowptr, al2s, al2d, den2, b2, out, e, n);
}

// Round 2
// 531.821 us; speedup vs baseline: 1.8625x; 1.8625x over previous
//
#include <hip/hip_runtime.h>
#include <hip/hip_bf16.h>
#include <cstdint>
#include <cstddef>

// ---------------------------------------------------------------------------
// FarmerGAT: 2-layer GAT on MI355X.
// Round 2: CSR stores resolved src idx; per-edge softmax weights precomputed
// in CSR order (atomic-free denominators); aggregation uses float4 gathers
// with 4 (layer1) / 16 (layer2) rows in flight per block.
// ---------------------------------------------------------------------------

static __device__ __forceinline__ float lrelu02(float x) { return x > 0.f ? x : 0.2f * x; }
static __device__ __forceinline__ float eluf(float x)    { return x > 0.f ? x : __expf(x) - 1.f; }

// --- edge dtype detect: int64 little-endian with values < 2^31 has zero odd words
__global__ void detect_kernel(const int* __restrict__ ei, int* __restrict__ flag, int e) {
    if (blockIdx.x == 0 && threadIdx.x == 0) {
        int zeros = 0;
        int m = e < 64 ? e : 64;
        for (int i = 0; i < m; ++i) if (ei[2 * i + 1] == 0) ++zeros;
        *flag = (zeros >= (m / 2 + 1)) ? 1 : 0;
    }
}

__global__ void convert_kernel(const int* __restrict__ ei, const int* __restrict__ flag,
                               int* __restrict__ es, int n2e) {
    int i = blockIdx.x * blockDim.x + threadIdx.x;
    if (i < n2e) es[i] = (*flag) ? ei[2 * i] : ei[i];
}

// --- CSR build ---
__global__ void hist_kernel(const int* __restrict__ dst, int* __restrict__ deg, int e, int et) {
    int i = blockIdx.x * blockDim.x + threadIdx.x;
    if (i < et) {
        int d = (i < e) ? dst[i] : (i - e);   // self loops appended
        atomicAdd(&deg[d], 1);
    }
}

// single-block exclusive scan (wave-shuffle based)
__global__ __launch_bounds__(1024) void scan_kernel(const int* __restrict__ deg,
                                                    int* __restrict__ rowptr, int n) {
    __shared__ int wsum[16];
    __shared__ int s_carry;
    int t = threadIdx.x, lane = t & 63, w = t >> 6;
    if (t == 0) s_carry = 0;
    __syncthreads();
    for (int base = 0; base < n; base += 1024) {
        int i = base + t;
        int v = (i < n) ? deg[i] : 0;
        int incl = v;
        #pragma unroll
        for (int d = 1; d < 64; d <<= 1) {
            int o = __shfl_up(incl, d);
            if (lane >= d) incl += o;
        }
        if (lane == 63) wsum[w] = incl;
        __syncthreads();
        if (w == 0 && lane < 16) {
            int s = wsum[lane];
            int si = s;
            #pragma unroll
            for (int d = 1; d < 16; d <<= 1) {
                int o = __shfl_up(si, d);
                if (lane >= d) si += o;
            }
            wsum[lane] = si - s;  // exclusive
        }
        __syncthreads();
        int excl = s_carry + wsum[w] + incl - v;
        if (i < n) rowptr[i] = excl;
        int tot = excl + v;
        __syncthreads();
        if (t == 1023) s_carry = tot;
        __syncthreads();
    }
    if (t == 0) rowptr[n] = s_carry;
}

// scatter resolved SOURCE index into CSR position (kills indirection in agg)
__global__ void scatter_kernel(const int* __restrict__ src, const int* __restrict__ dst,
                               int* __restrict__ cursor, int* __restrict__ sidx,
                               int e, int et) {
    int i = blockIdx.x * blockDim.x + threadIdx.x;
    if (i < et) {
        int d, s;
        if (i < e) { d = dst[i]; s = src[i]; } else { d = s = i - e; }
        int pos = atomicAdd(&cursor[d], 1);
        sidx[pos] = s;
    }
}

// --- fp32 tiled GEMM: C[M,N] = A[M,K] * B[K,N]; N multiple of 64, K multiple of 16
__global__ __launch_bounds__(256) void gemm_kernel(const float* __restrict__ A,
                                                   const float* __restrict__ B,
                                                   float* __restrict__ C,
                                                   int M, int N, int K) {
    __shared__ float As[16][64];
    __shared__ float Bs[16][64];
    int t = threadIdx.x;
    int tx = t & 15, ty = t >> 4;
    int bm = blockIdx.y * 64;
    int bn = blockIdx.x * 64;
    float acc[4][4] = {};
    for (int k0 = 0; k0 < K; k0 += 16) {
        {
            int row = t >> 2;
            int kk = (t & 3) * 4;
            int gr = bm + row;
            float4 a4 = (gr < M) ? *(const float4*)(A + (size_t)gr * K + k0 + kk)
                                 : make_float4(0.f, 0.f, 0.f, 0.f);
            As[kk + 0][row] = a4.x; As[kk + 1][row] = a4.y;
            As[kk + 2][row] = a4.z; As[kk + 3][row] = a4.w;
        }
        {
            int kr = t >> 4;
            int cc = (t & 15) * 4;
            float4 b4 = *(const float4*)(B + (size_t)(k0 + kr) * N + bn + cc);
            *(float4*)&Bs[kr][cc] = b4;
        }
        __syncthreads();
        #pragma unroll
        for (int kk = 0; kk < 16; ++kk) {
            float4 a4 = *(const float4*)&As[kk][ty * 4];
            float4 b4 = *(const float4*)&Bs[kk][tx * 4];
            float a[4] = {a4.x, a4.y, a4.z, a4.w};
            float b[4] = {b4.x, b4.y, b4.z, b4.w};
            #pragma unroll
            for (int i = 0; i < 4; ++i)
                #pragma unroll
                for (int j = 0; j < 4; ++j)
                    acc[i][j] += a[i] * b[j];
        }
        __syncthreads();
    }
    #pragma unroll
    for (int i = 0; i < 4; ++i) {
        int gr = bm + ty * 4 + i;
        if (gr < M) {
            float4 v = make_float4(acc[i][0], acc[i][1], acc[i][2], acc[i][3]);
            *(float4*)(C + (size_t)gr * N + bn + tx * 4) = v;
        }
    }
}

// --- attention logits, layer1 (4 heads x 64 ch): one wave per node
__global__ __launch_bounds__(256) void al_head4_kernel(const float* __restrict__ h1,
                                                       const float* __restrict__ a_src,
                                                       const float* __restrict__ a_dst,
                                                       float* __restrict__ als,
                                                       float* __restrict__ ald, int n) {
    int node = blockIdx.x * 4 + (threadIdx.x >> 6);
    int lane = threadIdx.x & 63;
    if (node >= n) return;
    #pragma unroll
    for (int h = 0; h < 4; ++h) {
        float v = h1[(size_t)node * 256 + h * 64 + lane];
        float ps = v * a_src[h * 64 + lane];
        float pd = v * a_dst[h * 64 + lane];
        #pragma unroll
        for (int d = 32; d > 0; d >>= 1) {
            ps += __shfl_down(ps, d);
            pd += __shfl_down(pd, d);
        }
        if (lane == 0) {
            als[node * 4 + h] = ps;
            ald[node * 4 + h] = pd;
        }
    }
}

// --- attention logits, layer2 (1 head x 64 ch): one wave per node
__global__ __launch_bounds__(256) void al_head1_kernel(const float* __restrict__ h2,
                                                       const float* __restrict__ a_src,
                                                       const float* __restrict__ a_dst,
                                                       float* __restrict__ als,
                                                       float* __restrict__ ald, int n) {
    int node = blockIdx.x * 4 + (threadIdx.x >> 6);
    int lane = threadIdx.x & 63;
    if (node >= n) return;
    float v = h2[(size_t)node * 64 + lane];
    float ps = v * a_src[lane];
    float pd = v * a_dst[lane];
    #pragma unroll
    for (int d = 32; d > 0; d >>= 1) {
        ps += __shfl_down(ps, d);
        pd += __shfl_down(pd, d);
    }
    if (lane == 0) {
        als[node] = ps;
        ald[node] = pd;
    }
}

// --- per-edge softmax weights in CSR order + denominators (atomic-free)
// 16 lanes per node; no max-subtraction: logits are O(+-8), fp32 exp is safe
__global__ __launch_bounds__(256) void weights1_kernel(const int* __restrict__ sidx,
                                                       const int* __restrict__ rowptr,
                                                       const float* __restrict__ als,
                                                       const float* __restrict__ ald,
                                                       float4* __restrict__ w4,
                                                       float4* __restrict__ den, int n) {
    int g = (blockIdx.x * 256 + threadIdx.x) >> 4;
    int l = threadIdx.x & 15;
    if (g >= n) return;
    float4 ad = ((const float4*)ald)[g];
    int p0 = rowptr[g], p1 = rowptr[g + 1];
    float4 acc = make_float4(0.f, 0.f, 0.f, 0.f);
    for (int p = p0 + l; p < p1; p += 16) {
        int s = sidx[p];
        float4 as = ((const float4*)als)[s];
        float4 wv;
        wv.x = __expf(lrelu02(as.x + ad.x));
        wv.y = __expf(lrelu02(as.y + ad.y));
        wv.z = __expf(lrelu02(as.z + ad.z));
        wv.w = __expf(lrelu02(as.w + ad.w));
        w4[p] = wv;
        acc.x += wv.x; acc.y += wv.y; acc.z += wv.z; acc.w += wv.w;
    }
    #pragma unroll
    for (int d = 8; d > 0; d >>= 1) {
        acc.x += __shfl_down(acc.x, d);
        acc.y += __shfl_down(acc.y, d);
        acc.z += __shfl_down(acc.z, d);
        acc.w += __shfl_down(acc.w, d);
    }
    if (l == 0) den[g] = acc;
}

__global__ __launch_bounds__(256) void weights2_kernel(const int* __restrict__ sidx,
                                                       const int* __restrict__ rowptr,
                                                       const float* __restrict__ als,
                                                       const float* __restrict__ ald,
                                                       float* __restrict__ w,
                                                       float* __restrict__ den, int n) {
    int g = (blockIdx.x * 256 + threadIdx.x) >> 4;
    int l = threadIdx.x & 15;
    if (g >= n) return;
    float ad = ald[g];
    int p0 = rowptr[g], p1 = rowptr[g + 1];
    float acc = 0.f;
    for (int p = p0 + l; p < p1; p += 16) {
        int s = sidx[p];
        float wv = __expf(lrelu02(als[s] + ad));
        w[p] = wv;
        acc += wv;
    }
    #pragma unroll
    for (int d = 8; d > 0; d >>= 1) acc += __shfl_down(acc, d);
    if (l == 0) den[g] = acc;
}

// --- layer1 aggregation: block=256=4 waves per node; each wave loads a whole
// 1KB h1 row as float4/lane; 4 rows in flight; LDS cross-wave reduce.
__global__ __launch_bounds__(256) void agg1_kernel(const float* __restrict__ h1,
                                                   const int* __restrict__ sidx,
                                                   const int* __restrict__ rowptr,
                                                   const float* __restrict__ w4,
                                                   const float* __restrict__ den,
                                                   const float* __restrict__ b1,
                                                   float* __restrict__ x2, int n) {
    __shared__ float4 red[4][64];
    int node = blockIdx.x;
    int t = threadIdx.x, wv = t >> 6, l = t & 63;
    int h = l >> 4;  // head of this lane's channel quad
    int p0 = rowptr[node], p1 = rowptr[node + 1];
    float4 acc = make_float4(0.f, 0.f, 0.f, 0.f);
    for (int p = p0 + wv; p < p1; p += 4) {
        int s = sidx[p];
        float wt = w4[p * 4 + h];
        float4 r = *(const float4*)(h1 + (size_t)s * 256 + l * 4);
        acc.x += wt * r.x; acc.y += wt * r.y; acc.z += wt * r.z; acc.w += wt * r.w;
    }
    red[wv][l] = acc;
    __syncthreads();
    if (wv == 0) {
        float4 a = red[0][l], b = red[1][l], c = red[2][l], d = red[3][l];
        float rd = 1.f / (den[node * 4 + h] + 1e-16f);
        float4 bias = *(const float4*)(b1 + l * 4);
        float4 o;
        o.x = eluf((a.x + b.x + c.x + d.x) * rd + bias.x);
        o.y = eluf((a.y + b.y + c.y + d.y) * rd + bias.y);
        o.z = eluf((a.z + b.z + c.z + d.z) * rd + bias.z);
        o.w = eluf((a.w + b.w + c.w + d.w) * rd + bias.w);
        *(float4*)(x2 + (size_t)node * 256 + l * 4) = o;
    }
}

// --- layer2 aggregation: 16 edge-slots x 16 channel-quads; 16 rows in flight
__global__ __launch_bounds__(256) void agg2_kernel(const float* __restrict__ h2,
                                                   const int* __restrict__ sidx,
                                                   const int* __restrict__ rowptr,
                                                   const float* __restrict__ w,
                                                   const float* __restrict__ den,
                                                   const float* __restrict__ b2,
                                                   float* __restrict__ out, int n) {
    __shared__ float4 red[16][17];  // +1 pad: epilogue reads column-wise
    int node = blockIdx.x;
    int t = threadIdx.x;
    int slot = t >> 4, cq = t & 15;
    int p0 = rowptr[node], p1 = rowptr[node + 1];
    float4 acc = make_float4(0.f, 0.f, 0.f, 0.f);
    for (int p = p0 + slot; p < p1; p += 16) {
        int s = sidx[p];
        float wt = w[p];
        float4 r = *(const float4*)(h2 + (size_t)s * 64 + cq * 4);
        acc.x += wt * r.x; acc.y += wt * r.y; acc.z += wt * r.z; acc.w += wt * r.w;
    }
    red[slot][cq] = acc;
    __syncthreads();
    if (t < 16) {
        float4 s = make_float4(0.f, 0.f, 0.f, 0.f);
        #pragma unroll
        for (int k = 0; k < 16; ++k) {
            float4 v = red[k][t];
            s.x += v.x; s.y += v.y; s.z += v.z; s.w += v.w;
        }
        float rd = 1.f / (den[node] + 1e-16f);
        float4 bias = *(const float4*)(b2 + t * 4);
        float4 o;
        o.x = eluf(s.x * rd + bias.x);
        o.y = eluf(s.y * rd + bias.y);
        o.z = eluf(s.z * rd + bias.z);
        o.w = eluf(s.w * rd + bias.w);
        *(float4*)(out + (size_t)node * 64 + t * 4) = o;
    }
}

extern "C" void kernel_launch(void* const* d_in, const int* in_sizes, int n_in,
                              void* d_out, int out_size, void* d_ws, size_t ws_size,
                              hipStream_t stream) {
    const float* x   = (const float*)d_in[0];
    const int*   ei  = (const int*)d_in[1];
    const float* W1  = (const float*)d_in[2];
    const float* as1 = (const float*)d_in[3];
    const float* ad1 = (const float*)d_in[4];
    const float* b1  = (const float*)d_in[5];
    const float* W2  = (const float*)d_in[6];
    const float* as2 = (const float*)d_in[7];
    const float* ad2 = (const float*)d_in[8];
    const float* b2  = (const float*)d_in[9];
    float* out = (float*)d_out;

    const int n  = in_sizes[0] / 128;  // 50000
    const int e  = in_sizes[1] / 2;    // 800000
    const int et = e + n;

    char* w = (char*)d_ws;
    size_t off = 0;
    auto take = [&](size_t bytes) -> void* {
        void* p = w + off;
        off = (off + bytes + 255) & ~(size_t)255;
        return p;
    };
    float* h1   = (float*)take((size_t)n * 256 * 4);
    float* x2   = (float*)take((size_t)n * 256 * 4);
    float* h2   = (float*)take((size_t)n * 64 * 4);
    float* al1s = (float*)take((size_t)n * 4 * 4);
    float* al1d = (float*)take((size_t)n * 4 * 4);
    float* den1 = (float*)take((size_t)n * 4 * 4);
    float* al2s = (float*)take((size_t)n * 4);
    float* al2d = (float*)take((size_t)n * 4);
    float* den2 = (float*)take((size_t)n * 4);
    float* w1e  = (float*)take((size_t)et * 4 * 4);  // per-edge weights, 4 heads
    float* w2e  = (float*)take((size_t)et * 4);      // per-edge weights, layer2
    int* deg    = (int*)take((size_t)(n + 1) * 4);
    int* rowptr = (int*)take((size_t)(n + 1) * 4);
    int* cursor = (int*)take((size_t)(n + 1) * 4);
    int* sidx   = (int*)take((size_t)et * 4);
    int* es     = (int*)take((size_t)2 * e * 4);
    int* flag   = (int*)take(256);

    // edge dtype normalize
    detect_kernel<<<1, 64, 0, stream>>>(ei, flag, e);
    int n2e = 2 * e;
    convert_kernel<<<(n2e + 255) / 256, 256, 0, stream>>>(ei, flag, es, n2e);
    const int* srcA = es;
    const int* dstA = es + e;

    hipMemsetAsync(deg, 0, (size_t)n * 4, stream);

    // CSR build (by dst) with resolved src indices; reused for both layers
    hist_kernel<<<(et + 255) / 256, 256, 0, stream>>>(dstA, deg, e, et);
    scan_kernel<<<1, 1024, 0, stream>>>(deg, rowptr, n);
    hipMemcpyAsync(cursor, rowptr, (size_t)n * 4, hipMemcpyDeviceToDevice, stream);
    scatter_kernel<<<(et + 255) / 256, 256, 0, stream>>>(srcA, dstA, cursor, sidx, e, et);

    const int wg_nodes = (n * 16 + 255) / 256;

    // ---- layer 1 ----
    gemm_kernel<<<dim3(256 / 64, (n + 63) / 64), 256, 0, stream>>>(x, W1, h1, n, 256, 128);
    al_head4_kernel<<<(n + 3) / 4, 256, 0, stream>>>(h1, as1, ad1, al1s, al1d, n);
    weights1_kernel<<<wg_nodes, 256, 0, stream>>>(sidx, rowptr, al1s, al1d,
                                                  (float4*)w1e, (float4*)den1, n);
    agg1_kernel<<<n, 256, 0, stream>>>(h1, sidx, rowptr, w1e, den1, b1, x2, n);

    // ---- layer 2 ----
    gemm_kernel<<<dim3(64 / 64, (n + 63) / 64), 256, 0, stream>>>(x2, W2, h2, n, 64, 256);
    al_head1_kernel<<<(n + 3) / 4, 256, 0, stream>>>(h2, as2, ad2, al2s, al2d, n);
    weights2_kernel<<<wg_nodes, 256, 0, stream>>>(sidx, rowptr, al2s, al2d, w2e, den2, n);
    agg2_kernel<<<n, 256, 0, stream>>>(h2, sidx, rowptr, w2e, den2, b2, out, n);
}

// Round 3
// 384.177 us; speedup vs baseline: 2.5783x; 1.3843x over previous
//
#include <hip/hip_runtime.h>
#include <hip/hip_bf16.h>
#include <cstdint>
#include <cstddef>

// ---------------------------------------------------------------------------
// FarmerGAT round 3: fp16 data plane (h1/x2/h2 stored as __fp16, halves gather
// bytes), fp16 MFMA GEMMs (16x16x32_f16, 64x64 tile), multi-block scan,
// 2-edges-per-wave agg1 with 2x unroll (16 rows in flight per block).
// Softmax kept in fp32; no max-subtraction (logits O(+-8), exp safe in fp32).
// ---------------------------------------------------------------------------

typedef float f32x4 __attribute__((ext_vector_type(4)));
typedef __fp16 f16x8 __attribute__((ext_vector_type(8)));
typedef __fp16 f16x4 __attribute__((ext_vector_type(4)));

static __device__ __forceinline__ float lrelu02(float x) { return x > 0.f ? x : 0.2f * x; }
static __device__ __forceinline__ float eluf(float x)    { return x > 0.f ? x : __expf(x) - 1.f; }

// --- edge dtype detect: int64 little-endian with values < 2^31 has zero odd words
__global__ void detect_kernel(const int* __restrict__ ei, int* __restrict__ flag, int e) {
    if (blockIdx.x == 0 && threadIdx.x == 0) {
        int zeros = 0;
        int m = e < 64 ? e : 64;
        for (int i = 0; i < m; ++i) if (ei[2 * i + 1] == 0) ++zeros;
        *flag = (zeros >= (m / 2 + 1)) ? 1 : 0;
    }
}

__global__ void convert_kernel(const int* __restrict__ ei, const int* __restrict__ flag,
                               int* __restrict__ es, int n2e) {
    int i = blockIdx.x * blockDim.x + threadIdx.x;
    if (i < n2e) es[i] = (*flag) ? ei[2 * i] : ei[i];
}

__global__ void f32_to_f16_kernel(const float* __restrict__ x, __fp16* __restrict__ xh, int n4) {
    int i = blockIdx.x * 256 + threadIdx.x;
    if (i < n4) {
        float4 v = ((const float4*)x)[i];
        f16x4 h;
        h[0] = (__fp16)v.x; h[1] = (__fp16)v.y; h[2] = (__fp16)v.z; h[3] = (__fp16)v.w;
        ((f16x4*)xh)[i] = h;
    }
}

// --- CSR build ---
__global__ void hist_kernel(const int* __restrict__ dst, int* __restrict__ deg, int e, int et) {
    int i = blockIdx.x * blockDim.x + threadIdx.x;
    if (i < et) {
        int d = (i < e) ? dst[i] : (i - e);   // self loops appended
        atomicAdd(&deg[d], 1);
    }
}

// 3-phase scan: per-block local exclusive scan (1024 elems/block)
__global__ __launch_bounds__(256) void scan_blocks_kernel(const int* __restrict__ deg,
                                                          int* __restrict__ loc,
                                                          int* __restrict__ bsum, int n) {
    __shared__ int wsum[4];
    int t = threadIdx.x, lane = t & 63, w = t >> 6;
    int base = blockIdx.x * 1024 + t * 4;
    int4 v = make_int4(0, 0, 0, 0);
    if (base + 3 < n) v = *(const int4*)(deg + base);
    else {
        if (base < n) v.x = deg[base];
        if (base + 1 < n) v.y = deg[base + 1];
        if (base + 2 < n) v.z = deg[base + 2];
        if (base + 3 < n) v.w = deg[base + 3];
    }
    int s = v.x + v.y + v.z + v.w;
    int incl = s;
    #pragma unroll
    for (int d = 1; d < 64; d <<= 1) { int o = __shfl_up(incl, d); if (lane >= d) incl += o; }
    if (lane == 63) wsum[w] = incl;
    __syncthreads();
    int woff = 0;
    for (int k = 0; k < w; ++k) woff += wsum[k];
    int excl = woff + incl - s;
    if (base < n) {
        int e0 = excl, e1 = e0 + v.x, e2 = e1 + v.y, e3 = e2 + v.z;
        loc[base] = e0;
        if (base + 1 < n) loc[base + 1] = e1;
        if (base + 2 < n) loc[base + 2] = e2;
        if (base + 3 < n) loc[base + 3] = e3;
    }
    if (t == 255) bsum[blockIdx.x] = woff + incl;
}

__global__ __launch_bounds__(256) void scan_sums_kernel(const int* __restrict__ bsum,
                                                        int* __restrict__ boff, int nb,
                                                        int* __restrict__ rowptr, int n) {
    __shared__ int ws[4];
    int t = threadIdx.x, lane = t & 63, w = t >> 6;
    int v = (t < nb) ? bsum[t] : 0;
    int incl = v;
    #pragma unroll
    for (int d = 1; d < 64; d <<= 1) { int o = __shfl_up(incl, d); if (lane >= d) incl += o; }
    if (lane == 63) ws[w] = incl;
    __syncthreads();
    int woff = 0;
    for (int k = 0; k < w; ++k) woff += ws[k];
    int excl = woff + incl - v;
    if (t < nb) boff[t] = excl;
    if (t == nb - 1) rowptr[n] = excl + v;
}

// finalize rowptr in place and init cursor (replaces d2d memcpy)
__global__ void scan_add_kernel(int* __restrict__ rowptr, const int* __restrict__ boff,
                                int* __restrict__ cursor, int n) {
    int i = blockIdx.x * 256 + threadIdx.x;
    if (i < n) {
        int v = rowptr[i] + boff[i >> 10];
        rowptr[i] = v;
        cursor[i] = v;
    }
}

// scatter resolved SOURCE index into CSR position
__global__ void scatter_kernel(const int* __restrict__ src, const int* __restrict__ dst,
                               int* __restrict__ cursor, int* __restrict__ sidx,
                               int e, int et) {
    int i = blockIdx.x * blockDim.x + threadIdx.x;
    if (i < et) {
        int d, s;
        if (i < e) { d = dst[i]; s = src[i]; } else { d = s = i - e; }
        int pos = atomicAdd(&cursor[d], 1);
        sidx[pos] = s;
    }
}

// --- fp16 MFMA GEMM: C[M,N] f16 = A[M,K] f16 * B[K,N] f32
// block 256 = 4 waves, tile 64x64; wave w -> cols w*16..+15, 4 m-tiles each.
// LDS: As[64][40] f16 (row-major [m][k]), Bst[64][40] f16 ([n][k]); epilogue
// transposes C through LDS for coalesced half8 stores.
__global__ __launch_bounds__(256) void gemm_f16_kernel(const __fp16* __restrict__ A,
                                                       const float* __restrict__ B,
                                                       __fp16* __restrict__ C,
                                                       int M, int N, int K) {
    __shared__ __fp16 sm[5120];
    #define AS(r, c)  sm[(r) * 40 + (c)]
    #define BST(r, c) sm[2560 + (r) * 40 + (c)]
    #define CS(r, c)  sm[(r) * 72 + (c)]
    int t = threadIdx.x;
    int wv = t >> 6, l = t & 63;
    int bm = blockIdx.y * 64, bn = blockIdx.x * 64;
    int lm = l & 15, kq = l >> 4;
    f32x4 zero = {0.f, 0.f, 0.f, 0.f};
    f32x4 acc[4] = {zero, zero, zero, zero};

    int arow = t >> 2, achunk = (t & 3) * 8;   // A staging: 64 rows x 4 chunks of 8 f16
    int bnn = t & 63, bkc = (t >> 6) * 8;      // B staging: 64 cols x 4 chunks of 8 k

    for (int k0 = 0; k0 < K; k0 += 32) {
        // stage A (already f16, row-major)
        {
            int gr = bm + arow;
            f16x8 av;
            if (gr < M) av = *(const f16x8*)(A + (size_t)gr * K + k0 + achunk);
            else { f16x8 z = {0,0,0,0,0,0,0,0}; av = z; }
            *(f16x8*)&AS(arow, achunk) = av;
        }
        // stage B with transpose + f32->f16
        {
            f16x8 bh;
            #pragma unroll
            for (int j = 0; j < 8; ++j)
                bh[j] = (__fp16)B[(size_t)(k0 + bkc + j) * N + bn + bnn];
            *(f16x8*)&BST(bnn, bkc) = bh;
        }
        __syncthreads();
        f16x8 bfrag = *(const f16x8*)&BST(wv * 16 + lm, kq * 8);
        #pragma unroll
        for (int mt = 0; mt < 4; ++mt) {
            f16x8 afrag = *(const f16x8*)&AS(mt * 16 + lm, kq * 8);
            acc[mt] = __builtin_amdgcn_mfma_f32_16x16x32_f16(afrag, bfrag, acc[mt], 0, 0, 0);
        }
        __syncthreads();
    }
    // epilogue: transpose through LDS (aliases As/Bst; synced above)
    #pragma unroll
    for (int mt = 0; mt < 4; ++mt)
        #pragma unroll
        for (int r = 0; r < 4; ++r)
            CS(mt * 16 + kq * 4 + r, wv * 16 + lm) = (__fp16)acc[mt][r];
    __syncthreads();
    {
        int row = t >> 2, ch = (t & 3) * 16;
        if (bm + row < M) {
            f16x8 c0 = *(const f16x8*)&CS(row, ch);
            f16x8 c1 = *(const f16x8*)&CS(row, ch + 8);
            f16x8* gp = (f16x8*)(C + (size_t)(bm + row) * N + bn + ch);
            gp[0] = c0; gp[1] = c1;
        }
    }
    #undef AS
    #undef BST
    #undef CS
}

// --- attention logits, layer1 (4 heads x 64 ch): one wave per node
__global__ __launch_bounds__(256) void al_head4_kernel(const __fp16* __restrict__ h1,
                                                       const float* __restrict__ a_src,
                                                       const float* __restrict__ a_dst,
                                                       float* __restrict__ als,
                                                       float* __restrict__ ald, int n) {
    int node = blockIdx.x * 4 + (threadIdx.x >> 6);
    int lane = threadIdx.x & 63;
    if (node >= n) return;
    #pragma unroll
    for (int h = 0; h < 4; ++h) {
        float v = (float)h1[(size_t)node * 256 + h * 64 + lane];
        float ps = v * a_src[h * 64 + lane];
        float pd = v * a_dst[h * 64 + lane];
        #pragma unroll
        for (int d = 32; d > 0; d >>= 1) {
            ps += __shfl_down(ps, d);
            pd += __shfl_down(pd, d);
        }
        if (lane == 0) {
            als[node * 4 + h] = ps;
            ald[node * 4 + h] = pd;
        }
    }
}

// --- attention logits, layer2 (1 head x 64 ch): one wave per node
__global__ __launch_bounds__(256) void al_head1_kernel(const __fp16* __restrict__ h2,
                                                       const float* __restrict__ a_src,
                                                       const float* __restrict__ a_dst,
                                                       float* __restrict__ als,
                                                       float* __restrict__ ald, int n) {
    int node = blockIdx.x * 4 + (threadIdx.x >> 6);
    int lane = threadIdx.x & 63;
    if (node >= n) return;
    float v = (float)h2[(size_t)node * 64 + lane];
    float ps = v * a_src[lane];
    float pd = v * a_dst[lane];
    #pragma unroll
    for (int d = 32; d > 0; d >>= 1) {
        ps += __shfl_down(ps, d);
        pd += __shfl_down(pd, d);
    }
    if (lane == 0) {
        als[node] = ps;
        ald[node] = pd;
    }
}

// --- per-edge softmax weights in CSR order + denominators (atomic-free)
__global__ __launch_bounds__(256) void weights1_kernel(const int* __restrict__ sidx,
                                                       const int* __restrict__ rowptr,
                                                       const float* __restrict__ als,
                                                       const float* __restrict__ ald,
                                                       float4* __restrict__ w4,
                                                       float4* __restrict__ den, int n) {
    int g = (blockIdx.x * 256 + threadIdx.x) >> 4;
    int l = threadIdx.x & 15;
    if (g >= n) return;
    float4 ad = ((const float4*)ald)[g];
    int p0 = rowptr[g], p1 = rowptr[g + 1];
    float4 acc = make_float4(0.f, 0.f, 0.f, 0.f);
    for (int p = p0 + l; p < p1; p += 16) {
        int s = sidx[p];
        float4 as = ((const float4*)als)[s];
        float4 wv;
        wv.x = __expf(lrelu02(as.x + ad.x));
        wv.y = __expf(lrelu02(as.y + ad.y));
        wv.z = __expf(lrelu02(as.z + ad.z));
        wv.w = __expf(lrelu02(as.w + ad.w));
        w4[p] = wv;
        acc.x += wv.x; acc.y += wv.y; acc.z += wv.z; acc.w += wv.w;
    }
    #pragma unroll
    for (int d = 8; d > 0; d >>= 1) {
        acc.x += __shfl_down(acc.x, d);
        acc.y += __shfl_down(acc.y, d);
        acc.z += __shfl_down(acc.z, d);
        acc.w += __shfl_down(acc.w, d);
    }
    if (l == 0) den[g] = acc;
}

__global__ __launch_bounds__(256) void weights2_kernel(const int* __restrict__ sidx,
                                                       const int* __restrict__ rowptr,
                                                       const float* __restrict__ als,
                                                       const float* __restrict__ ald,
                                                       float* __restrict__ w,
                                                       float* __restrict__ den, int n) {
    int g = (blockIdx.x * 256 + threadIdx.x) >> 4;
    int l = threadIdx.x & 15;
    if (g >= n) return;
    float ad = ald[g];
    int p0 = rowptr[g], p1 = rowptr[g + 1];
    float acc = 0.f;
    for (int p = p0 + l; p < p1; p += 16) {
        int s = sidx[p];
        float wv = __expf(lrelu02(als[s] + ad));
        w[p] = wv;
        acc += wv;
    }
    #pragma unroll
    for (int d = 8; d > 0; d >>= 1) acc += __shfl_down(acc, d);
    if (l == 0) den[g] = acc;
}

// --- layer1 aggregation: 4 waves/block, 2 edges per wave (32 lanes x 16B =
// one 512B fp16 row per half-wave), 2x unrolled -> 16 rows in flight.
__global__ __launch_bounds__(256) void agg1_kernel(const __fp16* __restrict__ h1,
                                                   const int* __restrict__ sidx,
                                                   const int* __restrict__ rowptr,
                                                   const float* __restrict__ w4,
                                                   const float* __restrict__ den,
                                                   const float* __restrict__ b1,
                                                   __fp16* __restrict__ x2, int n) {
    __shared__ float red[4][32][9];
    int node = blockIdx.x;
    int t = threadIdx.x, wv = t >> 6, l = t & 63;
    int le = l & 31, halfE = l >> 5;
    int c0 = le * 8;
    int head = le >> 3;
    int p0 = rowptr[node], p1 = rowptr[node + 1];
    float acc[8] = {0.f, 0.f, 0.f, 0.f, 0.f, 0.f, 0.f, 0.f};

    auto body = [&](int p) {
        int s = sidx[p];
        float wt = w4[p * 4 + head];
        f16x8 r = *(const f16x8*)(h1 + (size_t)s * 256 + c0);
        #pragma unroll
        for (int j = 0; j < 8; ++j) acc[j] += wt * (float)r[j];
    };
    int p = p0 + wv * 2 + halfE;
    for (; p + 8 < p1; p += 16) { body(p); body(p + 8); }
    if (p < p1) body(p);

    #pragma unroll
    for (int j = 0; j < 8; ++j) acc[j] += __shfl_down(acc[j], 32);
    if (l < 32) {
        #pragma unroll
        for (int j = 0; j < 8; ++j) red[wv][le][j] = acc[j];
    }
    __syncthreads();
    {
        int rle = t >> 3, j = t & 7;           // t = rle*8 + j = channel
        float s = red[0][rle][j] + red[1][rle][j] + red[2][rle][j] + red[3][rle][j];
        float rd = 1.f / (den[node * 4 + (t >> 6)] + 1e-16f);
        float v = s * rd + b1[t];
        x2[(size_t)node * 256 + t] = (__fp16)eluf(v);
    }
}

// --- layer2 aggregation: 16 edge-slots x 16 lanes (8B fp16 loads), 2x unroll
__global__ __launch_bounds__(256) void agg2_kernel(const __fp16* __restrict__ h2,
                                                   const int* __restrict__ sidx,
                                                   const int* __restrict__ rowptr,
                                                   const float* __restrict__ w,
                                                   const float* __restrict__ den,
                                                   const float* __restrict__ b2,
                                                   float* __restrict__ out, int n) {
    __shared__ float4 red[16][17];
    int node = blockIdx.x;
    int t = threadIdx.x;
    int slot = t >> 4, cq = t & 15;
    int p0 = rowptr[node], p1 = rowptr[node + 1];
    float4 acc = make_float4(0.f, 0.f, 0.f, 0.f);
    auto body = [&](int p) {
        int s = sidx[p];
        float wt = w[p];
        f16x4 r = *(const f16x4*)(h2 + (size_t)s * 64 + cq * 4);
        acc.x += wt * (float)r[0]; acc.y += wt * (float)r[1];
        acc.z += wt * (float)r[2]; acc.w += wt * (float)r[3];
    };
    int p = p0 + slot;
    for (; p + 16 < p1; p += 32) { body(p); body(p + 16); }
    if (p < p1) body(p);

    red[slot][cq] = acc;
    __syncthreads();
    if (t < 16) {
        float4 s = make_float4(0.f, 0.f, 0.f, 0.f);
        #pragma unroll
        for (int k = 0; k < 16; ++k) {
            float4 v = red[k][t];
            s.x += v.x; s.y += v.y; s.z += v.z; s.w += v.w;
        }
        float rd = 1.f / (den[node] + 1e-16f);
        float4 bias = *(const float4*)(b2 + t * 4);
        float4 o;
        o.x = eluf(s.x * rd + bias.x);
        o.y = eluf(s.y * rd + bias.y);
        o.z = eluf(s.z * rd + bias.z);
        o.w = eluf(s.w * rd + bias.w);
        *(float4*)(out + (size_t)node * 64 + t * 4) = o;
    }
}

extern "C" void kernel_launch(void* const* d_in, const int* in_sizes, int n_in,
                              void* d_out, int out_size, void* d_ws, size_t ws_size,
                              hipStream_t stream) {
    const float* x   = (const float*)d_in[0];
    const int*   ei  = (const int*)d_in[1];
    const float* W1  = (const float*)d_in[2];
    const float* as1 = (const float*)d_in[3];
    const float* ad1 = (const float*)d_in[4];
    const float* b1  = (const float*)d_in[5];
    const float* W2  = (const float*)d_in[6];
    const float* as2 = (const float*)d_in[7];
    const float* ad2 = (const float*)d_in[8];
    const float* b2  = (const float*)d_in[9];
    float* out = (float*)d_out;

    const int n  = in_sizes[0] / 128;  // 50000
    const int e  = in_sizes[1] / 2;    // 800000
    const int et = e + n;

    char* w = (char*)d_ws;
    size_t off = 0;
    auto take = [&](size_t bytes) -> void* {
        void* p = w + off;
        off = (off + bytes + 255) & ~(size_t)255;
        return p;
    };
    __fp16* xh  = (__fp16*)take((size_t)n * 128 * 2);
    __fp16* h1h = (__fp16*)take((size_t)n * 256 * 2);
    __fp16* x2h = (__fp16*)take((size_t)n * 256 * 2);
    __fp16* h2h = (__fp16*)take((size_t)n * 64 * 2);
    float* al1s = (float*)take((size_t)n * 4 * 4);
    float* al1d = (float*)take((size_t)n * 4 * 4);
    float* den1 = (float*)take((size_t)n * 4 * 4);
    float* al2s = (float*)take((size_t)n * 4);
    float* al2d = (float*)take((size_t)n * 4);
    float* den2 = (float*)take((size_t)n * 4);
    float* w1e  = (float*)take((size_t)et * 4 * 4);
    float* w2e  = (float*)take((size_t)et * 4);
    int* deg    = (int*)take((size_t)(n + 1) * 4);
    int* rowptr = (int*)take((size_t)(n + 1) * 4);
    int* cursor = (int*)take((size_t)(n + 1) * 4);
    int* sidx   = (int*)take((size_t)et * 4);
    int* es     = (int*)take((size_t)2 * e * 4);
    int* bsum   = (int*)take(1024);
    int* boff   = (int*)take(1024);
    int* flag   = (int*)take(256);

    // edge dtype normalize
    detect_kernel<<<1, 64, 0, stream>>>(ei, flag, e);
    int n2e = 2 * e;
    convert_kernel<<<(n2e + 255) / 256, 256, 0, stream>>>(ei, flag, es, n2e);
    const int* srcA = es;
    const int* dstA = es + e;

    // x -> fp16 (for MFMA GEMM1)
    f32_to_f16_kernel<<<(n * 128 / 4 + 255) / 256, 256, 0, stream>>>(x, xh, n * 128 / 4);

    hipMemsetAsync(deg, 0, (size_t)n * 4, stream);
    hist_kernel<<<(et + 255) / 256, 256, 0, stream>>>(dstA, deg, e, et);
    int nb = (n + 1023) / 1024;
    scan_blocks_kernel<<<nb, 256, 0, stream>>>(deg, rowptr, bsum, n);
    scan_sums_kernel<<<1, 256, 0, stream>>>(bsum, boff, nb, rowptr, n);
    scan_add_kernel<<<(n + 255) / 256, 256, 0, stream>>>(rowptr, boff, cursor, n);
    scatter_kernel<<<(et + 255) / 256, 256, 0, stream>>>(srcA, dstA, cursor, sidx, e, et);

    const int wg_nodes = (n * 16 + 255) / 256;
    const int mblocks = (n + 63) / 64;

    // ---- layer 1 ----
    gemm_f16_kernel<<<dim3(4, mblocks), 256, 0, stream>>>(xh, W1, h1h, n, 256, 128);
    al_head4_kernel<<<(n + 3) / 4, 256, 0, stream>>>(h1h, as1, ad1, al1s, al1d, n);
    weights1_kernel<<<wg_nodes, 256, 0, stream>>>(sidx, rowptr, al1s, al1d,
                                                  (float4*)w1e, (float4*)den1, n);
    agg1_kernel<<<n, 256, 0, stream>>>(h1h, sidx, rowptr, w1e, den1, b1, x2h, n);

    // ---- layer 2 ----
    gemm_f16_kernel<<<dim3(1, mblocks), 256, 0, stream>>>(x2h, W2, h2h, n, 64, 256);
    al_head1_kernel<<<(n + 3) / 4, 256, 0, stream>>>(h2h, as2, ad2, al2s, al2d, n);
    weights2_kernel<<<wg_nodes, 256, 0, stream>>>(sidx, rowptr, al2s, al2d, w2e, den2, n);
    agg2_kernel<<<n, 256, 0, stream>>>(h2h, sidx, rowptr, w2e, den2, b2, out, n);
}

// Round 4
// 327.300 us; speedup vs baseline: 3.0264x; 1.1738x over previous
//
#include <hip/hip_runtime.h>
#include <hip/hip_bf16.h>
#include <cstdint>
#include <cstddef>

// ---------------------------------------------------------------------------
// FarmerGAT round 4: wave-per-node aggregation (no LDS reduce, no syncthreads,
// no bank conflicts); attention logits fused into GEMM epilogues; fp16 data
// plane + fp16 MFMA GEMMs; multi-block scan CSR build.
// ---------------------------------------------------------------------------

typedef float f32x4 __attribute__((ext_vector_type(4)));
typedef __fp16 f16x8 __attribute__((ext_vector_type(8)));
typedef __fp16 f16x4 __attribute__((ext_vector_type(4)));

static __device__ __forceinline__ float lrelu02(float x) { return x > 0.f ? x : 0.2f * x; }
static __device__ __forceinline__ float eluf(float x)    { return x > 0.f ? x : __expf(x) - 1.f; }

// --- edge dtype detect: int64 little-endian with values < 2^31 has zero odd words
__global__ void detect_kernel(const int* __restrict__ ei, int* __restrict__ flag, int e) {
    if (blockIdx.x == 0 && threadIdx.x == 0) {
        int zeros = 0;
        int m = e < 64 ? e : 64;
        for (int i = 0; i < m; ++i) if (ei[2 * i + 1] == 0) ++zeros;
        *flag = (zeros >= (m / 2 + 1)) ? 1 : 0;
    }
}

__global__ void convert_kernel(const int* __restrict__ ei, const int* __restrict__ flag,
                               int* __restrict__ es, int n2e) {
    int i = blockIdx.x * blockDim.x + threadIdx.x;
    if (i < n2e) es[i] = (*flag) ? ei[2 * i] : ei[i];
}

__global__ void f32_to_f16_kernel(const float* __restrict__ x, __fp16* __restrict__ xh, int n4) {
    int i = blockIdx.x * 256 + threadIdx.x;
    if (i < n4) {
        float4 v = ((const float4*)x)[i];
        f16x4 h;
        h[0] = (__fp16)v.x; h[1] = (__fp16)v.y; h[2] = (__fp16)v.z; h[3] = (__fp16)v.w;
        ((f16x4*)xh)[i] = h;
    }
}

// --- CSR build ---
__global__ void hist_kernel(const int* __restrict__ dst, int* __restrict__ deg, int e, int et) {
    int i = blockIdx.x * blockDim.x + threadIdx.x;
    if (i < et) {
        int d = (i < e) ? dst[i] : (i - e);   // self loops appended
        atomicAdd(&deg[d], 1);
    }
}

// 3-phase scan: per-block local exclusive scan (1024 elems/block)
__global__ __launch_bounds__(256) void scan_blocks_kernel(const int* __restrict__ deg,
                                                          int* __restrict__ loc,
                                                          int* __restrict__ bsum, int n) {
    __shared__ int wsum[4];
    int t = threadIdx.x, lane = t & 63, w = t >> 6;
    int base = blockIdx.x * 1024 + t * 4;
    int4 v = make_int4(0, 0, 0, 0);
    if (base + 3 < n) v = *(const int4*)(deg + base);
    else {
        if (base < n) v.x = deg[base];
        if (base + 1 < n) v.y = deg[base + 1];
        if (base + 2 < n) v.z = deg[base + 2];
        if (base + 3 < n) v.w = deg[base + 3];
    }
    int s = v.x + v.y + v.z + v.w;
    int incl = s;
    #pragma unroll
    for (int d = 1; d < 64; d <<= 1) { int o = __shfl_up(incl, d); if (lane >= d) incl += o; }
    if (lane == 63) wsum[w] = incl;
    __syncthreads();
    int woff = 0;
    for (int k = 0; k < w; ++k) woff += wsum[k];
    int excl = woff + incl - s;
    if (base < n) {
        int e0 = excl, e1 = e0 + v.x, e2 = e1 + v.y, e3 = e2 + v.z;
        loc[base] = e0;
        if (base + 1 < n) loc[base + 1] = e1;
        if (base + 2 < n) loc[base + 2] = e2;
        if (base + 3 < n) loc[base + 3] = e3;
    }
    if (t == 255) bsum[blockIdx.x] = woff + incl;
}

__global__ __launch_bounds__(256) void scan_sums_kernel(const int* __restrict__ bsum,
                                                        int* __restrict__ boff, int nb,
                                                        int* __restrict__ rowptr, int n) {
    __shared__ int ws[4];
    int t = threadIdx.x, lane = t & 63, w = t >> 6;
    int v = (t < nb) ? bsum[t] : 0;
    int incl = v;
    #pragma unroll
    for (int d = 1; d < 64; d <<= 1) { int o = __shfl_up(incl, d); if (lane >= d) incl += o; }
    if (lane == 63) ws[w] = incl;
    __syncthreads();
    int woff = 0;
    for (int k = 0; k < w; ++k) woff += ws[k];
    int excl = woff + incl - v;
    if (t < nb) boff[t] = excl;
    if (t == nb - 1) rowptr[n] = excl + v;
}

// finalize rowptr in place and init cursor
__global__ void scan_add_kernel(int* __restrict__ rowptr, const int* __restrict__ boff,
                                int* __restrict__ cursor, int n) {
    int i = blockIdx.x * 256 + threadIdx.x;
    if (i < n) {
        int v = rowptr[i] + boff[i >> 10];
        rowptr[i] = v;
        cursor[i] = v;
    }
}

// scatter resolved SOURCE index into CSR position
__global__ void scatter_kernel(const int* __restrict__ src, const int* __restrict__ dst,
                               int* __restrict__ cursor, int* __restrict__ sidx,
                               int e, int et) {
    int i = blockIdx.x * blockDim.x + threadIdx.x;
    if (i < et) {
        int d, s;
        if (i < e) { d = dst[i]; s = src[i]; } else { d = s = i - e; }
        int pos = atomicAdd(&cursor[d], 1);
        sidx[pos] = s;
    }
}

// --- fp16 MFMA GEMM with fused attention-logit epilogue.
// C[M,N] f16 = A[M,K] f16 * B[K,N] f32; tile 64x64, block=256=4 waves.
// The 64-col tile at bn corresponds to head (bn>>6); epilogue computes
// als/ald[row*hstride + head] = sum_c C[row,c]*a_{src,dst}[bn+c].
__global__ __launch_bounds__(256) void gemm_f16_kernel(const __fp16* __restrict__ A,
                                                       const float* __restrict__ B,
                                                       __fp16* __restrict__ C,
                                                       const float* __restrict__ a_src,
                                                       const float* __restrict__ a_dst,
                                                       float* __restrict__ als,
                                                       float* __restrict__ ald,
                                                       int hstride,
                                                       int M, int N, int K) {
    __shared__ __fp16 sm[5120];
    #define AS(r, c)  sm[(r) * 40 + (c)]
    #define BST(r, c) sm[2560 + (r) * 40 + (c)]
    #define CS(r, c)  sm[(r) * 72 + (c)]
    int t = threadIdx.x;
    int wv = t >> 6, l = t & 63;
    int bm = blockIdx.y * 64, bn = blockIdx.x * 64;
    int lm = l & 15, kq = l >> 4;
    f32x4 zero = {0.f, 0.f, 0.f, 0.f};
    f32x4 acc[4] = {zero, zero, zero, zero};

    int arow = t >> 2, achunk = (t & 3) * 8;
    int bnn = t & 63, bkc = (t >> 6) * 8;

    for (int k0 = 0; k0 < K; k0 += 32) {
        {
            int gr = bm + arow;
            f16x8 av;
            if (gr < M) av = *(const f16x8*)(A + (size_t)gr * K + k0 + achunk);
            else { f16x8 z = {0,0,0,0,0,0,0,0}; av = z; }
            *(f16x8*)&AS(arow, achunk) = av;
        }
        {
            f16x8 bh;
            #pragma unroll
            for (int j = 0; j < 8; ++j)
                bh[j] = (__fp16)B[(size_t)(k0 + bkc + j) * N + bn + bnn];
            *(f16x8*)&BST(bnn, bkc) = bh;
        }
        __syncthreads();
        f16x8 bfrag = *(const f16x8*)&BST(wv * 16 + lm, kq * 8);
        #pragma unroll
        for (int mt = 0; mt < 4; ++mt) {
            f16x8 afrag = *(const f16x8*)&AS(mt * 16 + lm, kq * 8);
            acc[mt] = __builtin_amdgcn_mfma_f32_16x16x32_f16(afrag, bfrag, acc[mt], 0, 0, 0);
        }
        __syncthreads();
    }
    // transpose C through LDS
    #pragma unroll
    for (int mt = 0; mt < 4; ++mt)
        #pragma unroll
        for (int r = 0; r < 4; ++r)
            CS(mt * 16 + kq * 4 + r, wv * 16 + lm) = (__fp16)acc[mt][r];
    __syncthreads();
    {
        int row = t >> 2, ch = (t & 3) * 16;
        int gr = bm + row;
        f16x8 c0 = *(const f16x8*)&CS(row, ch);
        f16x8 c1 = *(const f16x8*)&CS(row, ch + 8);
        if (gr < M) {
            f16x8* gp = (f16x8*)(C + (size_t)gr * N + bn + ch);
            gp[0] = c0; gp[1] = c1;
        }
        // fused attention logits
        float ps = 0.f, pd = 0.f;
        #pragma unroll
        for (int j = 0; j < 8; ++j) {
            float v0 = (float)c0[j], v1 = (float)c1[j];
            ps += v0 * a_src[bn + ch + j] + v1 * a_src[bn + ch + 8 + j];
            pd += v0 * a_dst[bn + ch + j] + v1 * a_dst[bn + ch + 8 + j];
        }
        ps += __shfl_down(ps, 2); ps += __shfl_down(ps, 1);
        pd += __shfl_down(pd, 2); pd += __shfl_down(pd, 1);
        if ((t & 3) == 0 && gr < M) {
            int head = bn >> 6;
            als[gr * hstride + head] = ps;
            ald[gr * hstride + head] = pd;
        }
    }
    #undef AS
    #undef BST
    #undef CS
}

// --- per-edge softmax weights in CSR order + denominators (atomic-free)
__global__ __launch_bounds__(256) void weights1_kernel(const int* __restrict__ sidx,
                                                       const int* __restrict__ rowptr,
                                                       const float* __restrict__ als,
                                                       const float* __restrict__ ald,
                                                       float4* __restrict__ w4,
                                                       float4* __restrict__ den, int n) {
    int g = (blockIdx.x * 256 + threadIdx.x) >> 4;
    int l = threadIdx.x & 15;
    if (g >= n) return;
    float4 ad = ((const float4*)ald)[g];
    int p0 = rowptr[g], p1 = rowptr[g + 1];
    float4 acc = make_float4(0.f, 0.f, 0.f, 0.f);
    for (int p = p0 + l; p < p1; p += 16) {
        int s = sidx[p];
        float4 as = ((const float4*)als)[s];
        float4 wv;
        wv.x = __expf(lrelu02(as.x + ad.x));
        wv.y = __expf(lrelu02(as.y + ad.y));
        wv.z = __expf(lrelu02(as.z + ad.z));
        wv.w = __expf(lrelu02(as.w + ad.w));
        w4[p] = wv;
        acc.x += wv.x; acc.y += wv.y; acc.z += wv.z; acc.w += wv.w;
    }
    #pragma unroll
    for (int d = 8; d > 0; d >>= 1) {
        acc.x += __shfl_down(acc.x, d);
        acc.y += __shfl_down(acc.y, d);
        acc.z += __shfl_down(acc.z, d);
        acc.w += __shfl_down(acc.w, d);
    }
    if (l == 0) den[g] = acc;
}

__global__ __launch_bounds__(256) void weights2_kernel(const int* __restrict__ sidx,
                                                       const int* __restrict__ rowptr,
                                                       const float* __restrict__ als,
                                                       const float* __restrict__ ald,
                                                       float* __restrict__ w,
                                                       float* __restrict__ den, int n) {
    int g = (blockIdx.x * 256 + threadIdx.x) >> 4;
    int l = threadIdx.x & 15;
    if (g >= n) return;
    float ad = ald[g];
    int p0 = rowptr[g], p1 = rowptr[g + 1];
    float acc = 0.f;
    for (int p = p0 + l; p < p1; p += 16) {
        int s = sidx[p];
        float wv = __expf(lrelu02(als[s] + ad));
        w[p] = wv;
        acc += wv;
    }
    #pragma unroll
    for (int d = 8; d > 0; d >>= 1) acc += __shfl_down(acc, d);
    if (l == 0) den[g] = acc;
}

// --- layer1 aggregation: ONE WAVE PER NODE (4 nodes / 256-block).
// 2 half-wave edge slots x 2 unroll = 4 rows in flight per wave; single
// shfl_down(32) cross-half reduce; no LDS, no syncthreads.
__global__ __launch_bounds__(256) void agg1_kernel(const __fp16* __restrict__ h1,
                                                   const int* __restrict__ sidx,
                                                   const int* __restrict__ rowptr,
                                                   const float* __restrict__ w4,
                                                   const float* __restrict__ den,
                                                   const float* __restrict__ b1,
                                                   __fp16* __restrict__ x2, int n) {
    int t = threadIdx.x, wv = t >> 6, l = t & 63;
    int node = blockIdx.x * 4 + wv;
    if (node >= n) return;
    int le = l & 31, halfE = l >> 5;
    int head = le >> 3;
    int p0 = rowptr[node], p1 = rowptr[node + 1];
    float acc[8] = {0.f, 0.f, 0.f, 0.f, 0.f, 0.f, 0.f, 0.f};
    auto body = [&](int p) {
        int s = sidx[p];
        float wt = w4[p * 4 + head];
        f16x8 r = *(const f16x8*)(h1 + (size_t)s * 256 + le * 8);
        #pragma unroll
        for (int j = 0; j < 8; ++j) acc[j] += wt * (float)r[j];
    };
    int p = p0 + halfE;
    for (; p + 2 < p1; p += 4) { body(p); body(p + 2); }
    if (p < p1) body(p);
    #pragma unroll
    for (int j = 0; j < 8; ++j) acc[j] += __shfl_down(acc[j], 32);
    if (l < 32) {
        float rd = 1.f / (den[node * 4 + head] + 1e-16f);
        f16x8 o;
        #pragma unroll
        for (int j = 0; j < 8; ++j) {
            float v = acc[j] * rd + b1[le * 8 + j];
            o[j] = (__fp16)eluf(v);
        }
        *(f16x8*)(x2 + (size_t)node * 256 + le * 8) = o;
    }
}

// --- layer2 aggregation: ONE WAVE PER NODE; 8 slots x 8 lanes x 16B rows.
__global__ __launch_bounds__(256) void agg2_kernel(const __fp16* __restrict__ h2,
                                                   const int* __restrict__ sidx,
                                                   const int* __restrict__ rowptr,
                                                   const float* __restrict__ w,
                                                   const float* __restrict__ den,
                                                   const float* __restrict__ b2,
                                                   float* __restrict__ out, int n) {
    int t = threadIdx.x, wv = t >> 6, l = t & 63;
    int node = blockIdx.x * 4 + wv;
    if (node >= n) return;
    int slot = l >> 3, cq = l & 7;
    int p0 = rowptr[node], p1 = rowptr[node + 1];
    float acc[8] = {0.f, 0.f, 0.f, 0.f, 0.f, 0.f, 0.f, 0.f};
    auto body = [&](int p) {
        int s = sidx[p];
        float wt = w[p];
        f16x8 r = *(const f16x8*)(h2 + (size_t)s * 64 + cq * 8);
        #pragma unroll
        for (int j = 0; j < 8; ++j) acc[j] += wt * (float)r[j];
    };
    int p = p0 + slot;
    for (; p + 8 < p1; p += 16) { body(p); body(p + 8); }
    if (p < p1) body(p);
    #pragma unroll
    for (int j = 0; j < 8; ++j) {
        acc[j] += __shfl_down(acc[j], 32);
        acc[j] += __shfl_down(acc[j], 16);
        acc[j] += __shfl_down(acc[j], 8);
    }
    if (l < 8) {
        float rd = 1.f / (den[node] + 1e-16f);
        float4 o0, o1;
        o0.x = eluf(acc[0] * rd + b2[cq * 8 + 0]);
        o0.y = eluf(acc[1] * rd + b2[cq * 8 + 1]);
        o0.z = eluf(acc[2] * rd + b2[cq * 8 + 2]);
        o0.w = eluf(acc[3] * rd + b2[cq * 8 + 3]);
        o1.x = eluf(acc[4] * rd + b2[cq * 8 + 4]);
        o1.y = eluf(acc[5] * rd + b2[cq * 8 + 5]);
        o1.z = eluf(acc[6] * rd + b2[cq * 8 + 6]);
        o1.w = eluf(acc[7] * rd + b2[cq * 8 + 7]);
        float4* gp = (float4*)(out + (size_t)node * 64 + cq * 8);
        gp[0] = o0; gp[1] = o1;
    }
}

extern "C" void kernel_launch(void* const* d_in, const int* in_sizes, int n_in,
                              void* d_out, int out_size, void* d_ws, size_t ws_size,
                              hipStream_t stream) {
    const float* x   = (const float*)d_in[0];
    const int*   ei  = (const int*)d_in[1];
    const float* W1  = (const float*)d_in[2];
    const float* as1 = (const float*)d_in[3];
    const float* ad1 = (const float*)d_in[4];
    const float* b1  = (const float*)d_in[5];
    const float* W2  = (const float*)d_in[6];
    const float* as2 = (const float*)d_in[7];
    const float* ad2 = (const float*)d_in[8];
    const float* b2  = (const float*)d_in[9];
    float* out = (float*)d_out;

    const int n  = in_sizes[0] / 128;  // 50000
    const int e  = in_sizes[1] / 2;    // 800000
    const int et = e + n;

    char* w = (char*)d_ws;
    size_t off = 0;
    auto take = [&](size_t bytes) -> void* {
        void* p = w + off;
        off = (off + bytes + 255) & ~(size_t)255;
        return p;
    };
    __fp16* xh  = (__fp16*)take((size_t)n * 128 * 2);
    __fp16* h1h = (__fp16*)take((size_t)n * 256 * 2);
    __fp16* x2h = (__fp16*)take((size_t)n * 256 * 2);
    __fp16* h2h = (__fp16*)take((size_t)n * 64 * 2);
    float* al1s = (float*)take((size_t)n * 4 * 4);
    float* al1d = (float*)take((size_t)n * 4 * 4);
    float* den1 = (float*)take((size_t)n * 4 * 4);
    float* al2s = (float*)take((size_t)n * 4);
    float* al2d = (float*)take((size_t)n * 4);
    float* den2 = (float*)take((size_t)n * 4);
    float* w1e  = (float*)take((size_t)et * 4 * 4);
    float* w2e  = (float*)take((size_t)et * 4);
    int* deg    = (int*)take((size_t)(n + 1) * 4);
    int* rowptr = (int*)take((size_t)(n + 1) * 4);
    int* cursor = (int*)take((size_t)(n + 1) * 4);
    int* sidx   = (int*)take((size_t)et * 4);
    int* es     = (int*)take((size_t)2 * e * 4);
    int* bsum   = (int*)take(1024);
    int* boff   = (int*)take(1024);
    int* flag   = (int*)take(256);

    // edge dtype normalize
    detect_kernel<<<1, 64, 0, stream>>>(ei, flag, e);
    int n2e = 2 * e;
    convert_kernel<<<(n2e + 255) / 256, 256, 0, stream>>>(ei, flag, es, n2e);
    const int* srcA = es;
    const int* dstA = es + e;

    // x -> fp16 (for MFMA GEMM1)
    f32_to_f16_kernel<<<(n * 128 / 4 + 255) / 256, 256, 0, stream>>>(x, xh, n * 128 / 4);

    hipMemsetAsync(deg, 0, (size_t)n * 4, stream);
    hist_kernel<<<(et + 255) / 256, 256, 0, stream>>>(dstA, deg, e, et);
    int nb = (n + 1023) / 1024;
    scan_blocks_kernel<<<nb, 256, 0, stream>>>(deg, rowptr, bsum, n);
    scan_sums_kernel<<<1, 256, 0, stream>>>(bsum, boff, nb, rowptr, n);
    scan_add_kernel<<<(n + 255) / 256, 256, 0, stream>>>(rowptr, boff, cursor, n);
    scatter_kernel<<<(et + 255) / 256, 256, 0, stream>>>(srcA, dstA, cursor, sidx, e, et);

    const int wg_nodes = (n * 16 + 255) / 256;
    const int mblocks = (n + 63) / 64;
    const int nodeblocks = (n + 3) / 4;

    // ---- layer 1 ----
    gemm_f16_kernel<<<dim3(4, mblocks), 256, 0, stream>>>(xh, W1, h1h, as1, ad1,
                                                          al1s, al1d, 4, n, 256, 128);
    weights1_kernel<<<wg_nodes, 256, 0, stream>>>(sidx, rowptr, al1s, al1d,
                                                  (float4*)w1e, (float4*)den1, n);
    agg1_kernel<<<nodeblocks, 256, 0, stream>>>(h1h, sidx, rowptr, w1e, den1, b1, x2h, n);

    // ---- layer 2 ----
    gemm_f16_kernel<<<dim3(1, mblocks), 256, 0, stream>>>(x2h, W2, h2h, as2, ad2,
                                                          al2s, al2d, 1, n, 64, 256);
    weights2_kernel<<<wg_nodes, 256, 0, stream>>>(sidx, rowptr, al2s, al2d, w2e, den2, n);
    agg2_kernel<<<nodeblocks, 256, 0, stream>>>(h2h, sidx, rowptr, w2e, den2, b2, out, n);
}

// Round 5
// 311.684 us; speedup vs baseline: 3.1780x; 1.0501x over previous
//
#include <hip/hip_runtime.h>
#include <hip/hip_bf16.h>
#include <cstdint>
#include <cstddef>

// ---------------------------------------------------------------------------
// FarmerGAT round 5: softmax weights + denominator fused INTO aggregation
// (accumulate acc += w*h and accw += w in one loop; divide at end) -- the
// weights1/weights2/den passes are gone. gemm1 is full-width (A read once,
// f32->f16 inline). Attention logits fused in GEMM epilogues. CSR build:
// convert+hist fused, self-loops folded into scan (+1).
// ---------------------------------------------------------------------------

typedef float f32x4 __attribute__((ext_vector_type(4)));
typedef __fp16 f16x8 __attribute__((ext_vector_type(8)));
typedef __fp16 f16x4 __attribute__((ext_vector_type(4)));

static __device__ __forceinline__ float lrelu02(float x) { return x > 0.f ? x : 0.2f * x; }
static __device__ __forceinline__ float eluf(float x)    { return x > 0.f ? x : __expf(x) - 1.f; }

// --- edge dtype detect: int64 little-endian with values < 2^31 has zero odd words
__global__ void detect_kernel(const int* __restrict__ ei, int* __restrict__ flag, int e) {
    if (blockIdx.x == 0 && threadIdx.x == 0) {
        int zeros = 0;
        int m = e < 64 ? e : 64;
        for (int i = 0; i < m; ++i) if (ei[2 * i + 1] == 0) ++zeros;
        *flag = (zeros >= (m / 2 + 1)) ? 1 : 0;
    }
}

// --- fused edge convert + dst histogram (deg pre-zeroed; self-loops added in scan)
__global__ void convert_hist_kernel(const int* __restrict__ ei, const int* __restrict__ flag,
                                    int* __restrict__ es, int* __restrict__ deg, int e) {
    int i = blockIdx.x * 256 + threadIdx.x;
    if (i < e) {
        int f = *flag;
        int s = f ? ei[2 * i] : ei[i];
        int d = f ? ei[2 * (e + i)] : ei[e + i];
        es[i] = s;
        es[e + i] = d;
        atomicAdd(&deg[d], 1);
    }
}

// 3-phase scan; each node contributes deg[i]+1 (the +1 is its self-loop)
__global__ __launch_bounds__(256) void scan_blocks_kernel(const int* __restrict__ deg,
                                                          int* __restrict__ loc,
                                                          int* __restrict__ bsum, int n) {
    __shared__ int wsum[4];
    int t = threadIdx.x, lane = t & 63, w = t >> 6;
    int base = blockIdx.x * 1024 + t * 4;
    int4 v = make_int4(0, 0, 0, 0);
    if (base + 3 < n) {
        v = *(const int4*)(deg + base);
        v.x += 1; v.y += 1; v.z += 1; v.w += 1;
    } else {
        if (base < n) v.x = deg[base] + 1;
        if (base + 1 < n) v.y = deg[base + 1] + 1;
        if (base + 2 < n) v.z = deg[base + 2] + 1;
        if (base + 3 < n) v.w = deg[base + 3] + 1;
    }
    int s = v.x + v.y + v.z + v.w;
    int incl = s;
    #pragma unroll
    for (int d = 1; d < 64; d <<= 1) { int o = __shfl_up(incl, d); if (lane >= d) incl += o; }
    if (lane == 63) wsum[w] = incl;
    __syncthreads();
    int woff = 0;
    for (int k = 0; k < w; ++k) woff += wsum[k];
    int excl = woff + incl - s;
    if (base < n) {
        int e0 = excl, e1 = e0 + v.x, e2 = e1 + v.y, e3 = e2 + v.z;
        loc[base] = e0;
        if (base + 1 < n) loc[base + 1] = e1;
        if (base + 2 < n) loc[base + 2] = e2;
        if (base + 3 < n) loc[base + 3] = e3;
    }
    if (t == 255) bsum[blockIdx.x] = woff + incl;
}

__global__ __launch_bounds__(256) void scan_sums_kernel(const int* __restrict__ bsum,
                                                        int* __restrict__ boff, int nb,
                                                        int* __restrict__ rowptr, int n) {
    __shared__ int ws[4];
    int t = threadIdx.x, lane = t & 63, w = t >> 6;
    int v = (t < nb) ? bsum[t] : 0;
    int incl = v;
    #pragma unroll
    for (int d = 1; d < 64; d <<= 1) { int o = __shfl_up(incl, d); if (lane >= d) incl += o; }
    if (lane == 63) ws[w] = incl;
    __syncthreads();
    int woff = 0;
    for (int k = 0; k < w; ++k) woff += ws[k];
    int excl = woff + incl - v;
    if (t < nb) boff[t] = excl;
    if (t == nb - 1) rowptr[n] = excl + v;
}

__global__ void scan_add_kernel(int* __restrict__ rowptr, const int* __restrict__ boff,
                                int* __restrict__ cursor, int n) {
    int i = blockIdx.x * 256 + threadIdx.x;
    if (i < n) {
        int v = rowptr[i] + boff[i >> 10];
        rowptr[i] = v;
        cursor[i] = v;
    }
}

// scatter resolved SOURCE index into CSR position
__global__ void scatter_kernel(const int* __restrict__ src, const int* __restrict__ dst,
                               int* __restrict__ cursor, int* __restrict__ sidx,
                               int e, int et) {
    int i = blockIdx.x * blockDim.x + threadIdx.x;
    if (i < et) {
        int d, s;
        if (i < e) { d = dst[i]; s = src[i]; } else { d = s = i - e; }
        int pos = atomicAdd(&cursor[d], 1);
        sidx[pos] = s;
    }
}

// --- GEMM1: C[M,256] f16 = A[M,128] f32 * B[128,256] f32, f32->f16 inline.
// Block = 256 thr = 4 waves; tile 64 rows x FULL 256 cols (A read once).
// Fused epilogue: each thread owns (row, head) -> als/ald[row*4+head].
__global__ __launch_bounds__(256) void gemm1_kernel(const float* __restrict__ A,
                                                    const float* __restrict__ B,
                                                    __fp16* __restrict__ C,
                                                    const float* __restrict__ a_src,
                                                    const float* __restrict__ a_dst,
                                                    float* __restrict__ als,
                                                    float* __restrict__ ald, int M) {
    constexpr int N = 256, K = 128;
    __shared__ __fp16 sm[17920];                  // 35840 B
    #define AS(r, c)  sm[(r) * 40 + (c)]         // [64][40]
    #define BST(r, c) sm[2560 + (r) * 40 + (c)]  // [256][40], [n][k]
    #define CS(r, c)  sm[(r) * 264 + (c)]        // [64][264] (aliases AS/BST)
    float* sa = (float*)(sm + 16896);             // 256 f32
    float* sd = (float*)(sm + 17408);
    int t = threadIdx.x;
    int wv = t >> 6, l = t & 63;
    int lm = l & 15, kq = l >> 4;
    int bm = blockIdx.x * 64;
    sa[t] = a_src[t];
    sd[t] = a_dst[t];
    f32x4 zero = {0.f, 0.f, 0.f, 0.f};
    f32x4 acc[4][4] = {{zero, zero, zero, zero}, {zero, zero, zero, zero},
                       {zero, zero, zero, zero}, {zero, zero, zero, zero}};
    int arow = t >> 2, achunk = (t & 3) * 8;
    for (int k0 = 0; k0 < K; k0 += 32) {
        {   // stage A with f32->f16
            int gr = bm + arow;
            f16x8 av;
            if (gr < M) {
                float4 a0 = *(const float4*)(A + (size_t)gr * K + k0 + achunk);
                float4 a1 = *(const float4*)(A + (size_t)gr * K + k0 + achunk + 4);
                av[0] = (__fp16)a0.x; av[1] = (__fp16)a0.y; av[2] = (__fp16)a0.z; av[3] = (__fp16)a0.w;
                av[4] = (__fp16)a1.x; av[5] = (__fp16)a1.y; av[6] = (__fp16)a1.z; av[7] = (__fp16)a1.w;
            } else { f16x8 z = {0,0,0,0,0,0,0,0}; av = z; }
            *(f16x8*)&AS(arow, achunk) = av;
        }
        {   // stage B transposed: col = t, 4 chunks of 8 k
            #pragma unroll
            for (int bc = 0; bc < 4; ++bc) {
                f16x8 bh;
                #pragma unroll
                for (int j = 0; j < 8; ++j)
                    bh[j] = (__fp16)B[(size_t)(k0 + bc * 8 + j) * N + t];
                *(f16x8*)&BST(t, bc * 8) = bh;
            }
        }
        __syncthreads();
        #pragma unroll
        for (int nt = 0; nt < 4; ++nt) {
            f16x8 bfrag = *(const f16x8*)&BST(wv * 64 + nt * 16 + lm, kq * 8);
            #pragma unroll
            for (int mt = 0; mt < 4; ++mt) {
                f16x8 afrag = *(const f16x8*)&AS(mt * 16 + lm, kq * 8);
                acc[mt][nt] = __builtin_amdgcn_mfma_f32_16x16x32_f16(afrag, bfrag, acc[mt][nt], 0, 0, 0);
            }
        }
        __syncthreads();
    }
    // transpose C through LDS
    #pragma unroll
    for (int mt = 0; mt < 4; ++mt)
        #pragma unroll
        for (int nt = 0; nt < 4; ++nt)
            #pragma unroll
            for (int r = 0; r < 4; ++r)
                CS(mt * 16 + kq * 4 + r, wv * 64 + nt * 16 + lm) = (__fp16)acc[mt][nt][r];
    __syncthreads();
    {
        int row = t >> 2, head = t & 3;
        int gr = bm + row;
        f16x8 c[8];
        #pragma unroll
        for (int q = 0; q < 8; ++q) c[q] = *(const f16x8*)&CS(row, head * 64 + q * 8);
        float ps = 0.f, pd = 0.f;
        #pragma unroll
        for (int q = 0; q < 8; ++q)
            #pragma unroll
            for (int j = 0; j < 8; ++j) {
                float v = (float)c[q][j];
                ps += v * sa[head * 64 + q * 8 + j];
                pd += v * sd[head * 64 + q * 8 + j];
            }
        if (gr < M) {
            f16x8* gp = (f16x8*)(C + (size_t)gr * 256 + head * 64);
            #pragma unroll
            for (int q = 0; q < 8; ++q) gp[q] = c[q];
            als[gr * 4 + head] = ps;
            ald[gr * 4 + head] = pd;
        }
    }
    #undef AS
    #undef BST
    #undef CS
}

// --- GEMM2: C[M,64] f16 = A[M,256] f16 * B[256,64] f32; tile 64x64.
// Fused single-head logit epilogue.
__global__ __launch_bounds__(256) void gemm2_kernel(const __fp16* __restrict__ A,
                                                    const float* __restrict__ B,
                                                    __fp16* __restrict__ C,
                                                    const float* __restrict__ a_src,
                                                    const float* __restrict__ a_dst,
                                                    float* __restrict__ als,
                                                    float* __restrict__ ald,
                                                    int M, int N, int K) {
    __shared__ __fp16 sm[5120];
    #define AS(r, c)  sm[(r) * 40 + (c)]
    #define BST(r, c) sm[2560 + (r) * 40 + (c)]
    #define CS(r, c)  sm[(r) * 72 + (c)]
    int t = threadIdx.x;
    int wv = t >> 6, l = t & 63;
    int bm = blockIdx.x * 64;
    int lm = l & 15, kq = l >> 4;
    f32x4 zero = {0.f, 0.f, 0.f, 0.f};
    f32x4 acc[4] = {zero, zero, zero, zero};
    int arow = t >> 2, achunk = (t & 3) * 8;
    int bnn = t & 63, bkc = (t >> 6) * 8;
    for (int k0 = 0; k0 < K; k0 += 32) {
        {
            int gr = bm + arow;
            f16x8 av;
            if (gr < M) av = *(const f16x8*)(A + (size_t)gr * K + k0 + achunk);
            else { f16x8 z = {0,0,0,0,0,0,0,0}; av = z; }
            *(f16x8*)&AS(arow, achunk) = av;
        }
        {
            f16x8 bh;
            #pragma unroll
            for (int j = 0; j < 8; ++j)
                bh[j] = (__fp16)B[(size_t)(k0 + bkc + j) * N + bnn];
            *(f16x8*)&BST(bnn, bkc) = bh;
        }
        __syncthreads();
        f16x8 bfrag = *(const f16x8*)&BST(wv * 16 + lm, kq * 8);
        #pragma unroll
        for (int mt = 0; mt < 4; ++mt) {
            f16x8 afrag = *(const f16x8*)&AS(mt * 16 + lm, kq * 8);
            acc[mt] = __builtin_amdgcn_mfma_f32_16x16x32_f16(afrag, bfrag, acc[mt], 0, 0, 0);
        }
        __syncthreads();
    }
    #pragma unroll
    for (int mt = 0; mt < 4; ++mt)
        #pragma unroll
        for (int r = 0; r < 4; ++r)
            CS(mt * 16 + kq * 4 + r, wv * 16 + lm) = (__fp16)acc[mt][r];
    __syncthreads();
    {
        int row = t >> 2, ch = (t & 3) * 16;
        int gr = bm + row;
        f16x8 c0 = *(const f16x8*)&CS(row, ch);
        f16x8 c1 = *(const f16x8*)&CS(row, ch + 8);
        if (gr < M) {
            f16x8* gp = (f16x8*)(C + (size_t)gr * N + ch);
            gp[0] = c0; gp[1] = c1;
        }
        float ps = 0.f, pd = 0.f;
        #pragma unroll
        for (int j = 0; j < 8; ++j) {
            float v0 = (float)c0[j], v1 = (float)c1[j];
            ps += v0 * a_src[ch + j] + v1 * a_src[ch + 8 + j];
            pd += v0 * a_dst[ch + j] + v1 * a_dst[ch + 8 + j];
        }
        ps += __shfl_down(ps, 2); ps += __shfl_down(ps, 1);
        pd += __shfl_down(pd, 2); pd += __shfl_down(pd, 1);
        if ((t & 3) == 0 && gr < M) {
            als[gr] = ps;
            ald[gr] = pd;
        }
    }
    #undef AS
    #undef BST
    #undef CS
}

// --- layer1 aggregation with FUSED softmax: one wave per node.
// acc += w*h and accw += w in one loop; divide at the end. No weights pass.
__global__ __launch_bounds__(256) void agg1_kernel(const __fp16* __restrict__ h1,
                                                   const int* __restrict__ sidx,
                                                   const int* __restrict__ rowptr,
                                                   const float* __restrict__ als,
                                                   const float* __restrict__ ald,
                                                   const float* __restrict__ b1,
                                                   __fp16* __restrict__ x2, int n) {
    int t = threadIdx.x, wv = t >> 6, l = t & 63;
    int node = blockIdx.x * 4 + wv;
    if (node >= n) return;
    int le = l & 31, halfE = l >> 5;
    int head = le >> 3;
    float aldn = ald[node * 4 + head];
    int p0 = rowptr[node], p1 = rowptr[node + 1];
    float acc[8] = {0.f, 0.f, 0.f, 0.f, 0.f, 0.f, 0.f, 0.f};
    float accw = 0.f;
    auto body = [&](int p) {
        int s = sidx[p];
        float wt = __expf(lrelu02(als[s * 4 + head] + aldn));
        accw += wt;
        f16x8 r = *(const f16x8*)(h1 + (size_t)s * 256 + le * 8);
        #pragma unroll
        for (int j = 0; j < 8; ++j) acc[j] += wt * (float)r[j];
    };
    int p = p0 + halfE;
    for (; p + 2 < p1; p += 4) { body(p); body(p + 2); }
    if (p < p1) body(p);
    #pragma unroll
    for (int j = 0; j < 8; ++j) acc[j] += __shfl_down(acc[j], 32);
    accw += __shfl_down(accw, 32);
    if (l < 32) {
        float rd = 1.f / (accw + 1e-16f);
        f16x8 o;
        #pragma unroll
        for (int j = 0; j < 8; ++j) {
            float v = acc[j] * rd + b1[le * 8 + j];
            o[j] = (__fp16)eluf(v);
        }
        *(f16x8*)(x2 + (size_t)node * 256 + le * 8) = o;
    }
}

// --- layer2 aggregation with FUSED softmax: one wave per node; 8 slots x 8 lanes.
__global__ __launch_bounds__(256) void agg2_kernel(const __fp16* __restrict__ h2,
                                                   const int* __restrict__ sidx,
                                                   const int* __restrict__ rowptr,
                                                   const float* __restrict__ als,
                                                   const float* __restrict__ ald,
                                                   const float* __restrict__ b2,
                                                   float* __restrict__ out, int n) {
    int t = threadIdx.x, wv = t >> 6, l = t & 63;
    int node = blockIdx.x * 4 + wv;
    if (node >= n) return;
    int slot = l >> 3, cq = l & 7;
    float aldn = ald[node];
    int p0 = rowptr[node], p1 = rowptr[node + 1];
    float acc[8] = {0.f, 0.f, 0.f, 0.f, 0.f, 0.f, 0.f, 0.f};
    float accw = 0.f;
    auto body = [&](int p) {
        int s = sidx[p];
        float wt = __expf(lrelu02(als[s] + aldn));
        accw += wt;
        f16x8 r = *(const f16x8*)(h2 + (size_t)s * 64 + cq * 8);
        #pragma unroll
        for (int j = 0; j < 8; ++j) acc[j] += wt * (float)r[j];
    };
    int p = p0 + slot;
    for (; p + 8 < p1; p += 16) { body(p); body(p + 8); }
    if (p < p1) body(p);
    #pragma unroll
    for (int j = 0; j < 8; ++j) {
        acc[j] += __shfl_down(acc[j], 32);
        acc[j] += __shfl_down(acc[j], 16);
        acc[j] += __shfl_down(acc[j], 8);
    }
    accw += __shfl_down(accw, 32);
    accw += __shfl_down(accw, 16);
    accw += __shfl_down(accw, 8);
    if (l < 8) {
        float rd = 1.f / (accw + 1e-16f);
        float4 o0, o1;
        o0.x = eluf(acc[0] * rd + b2[cq * 8 + 0]);
        o0.y = eluf(acc[1] * rd + b2[cq * 8 + 1]);
        o0.z = eluf(acc[2] * rd + b2[cq * 8 + 2]);
        o0.w = eluf(acc[3] * rd + b2[cq * 8 + 3]);
        o1.x = eluf(acc[4] * rd + b2[cq * 8 + 4]);
        o1.y = eluf(acc[5] * rd + b2[cq * 8 + 5]);
        o1.z = eluf(acc[6] * rd + b2[cq * 8 + 6]);
        o1.w = eluf(acc[7] * rd + b2[cq * 8 + 7]);
        float4* gp = (float4*)(out + (size_t)node * 64 + cq * 8);
        gp[0] = o0; gp[1] = o1;
    }
}

extern "C" void kernel_launch(void* const* d_in, const int* in_sizes, int n_in,
                              void* d_out, int out_size, void* d_ws, size_t ws_size,
                              hipStream_t stream) {
    const float* x   = (const float*)d_in[0];
    const int*   ei  = (const int*)d_in[1];
    const float* W1  = (const float*)d_in[2];
    const float* as1 = (const float*)d_in[3];
    const float* ad1 = (const float*)d_in[4];
    const float* b1  = (const float*)d_in[5];
    const float* W2  = (const float*)d_in[6];
    const float* as2 = (const float*)d_in[7];
    const float* ad2 = (const float*)d_in[8];
    const float* b2  = (const float*)d_in[9];
    float* out = (float*)d_out;

    const int n  = in_sizes[0] / 128;  // 50000
    const int e  = in_sizes[1] / 2;    // 800000
    const int et = e + n;

    char* w = (char*)d_ws;
    size_t off = 0;
    auto take = [&](size_t bytes) -> void* {
        void* p = w + off;
        off = (off + bytes + 255) & ~(size_t)255;
        return p;
    };
    __fp16* h1h = (__fp16*)take((size_t)n * 256 * 2);
    __fp16* x2h = (__fp16*)take((size_t)n * 256 * 2);
    __fp16* h2h = (__fp16*)take((size_t)n * 64 * 2);
    float* al1s = (float*)take((size_t)n * 4 * 4);
    float* al1d = (float*)take((size_t)n * 4 * 4);
    float* al2s = (float*)take((size_t)n * 4);
    float* al2d = (float*)take((size_t)n * 4);
    int* deg    = (int*)take((size_t)(n + 1) * 4);
    int* rowptr = (int*)take((size_t)(n + 1) * 4);
    int* cursor = (int*)take((size_t)(n + 1) * 4);
    int* sidx   = (int*)take((size_t)et * 4);
    int* es     = (int*)take((size_t)2 * e * 4);
    int* bsum   = (int*)take(1024);
    int* boff   = (int*)take(1024);
    int* flag   = (int*)take(256);

    // edge dtype normalize + histogram (one pass)
    detect_kernel<<<1, 64, 0, stream>>>(ei, flag, e);
    hipMemsetAsync(deg, 0, (size_t)n * 4, stream);
    convert_hist_kernel<<<(e + 255) / 256, 256, 0, stream>>>(ei, flag, es, deg, e);
    const int* srcA = es;
    const int* dstA = es + e;

    int nb = (n + 1023) / 1024;
    scan_blocks_kernel<<<nb, 256, 0, stream>>>(deg, rowptr, bsum, n);
    scan_sums_kernel<<<1, 256, 0, stream>>>(bsum, boff, nb, rowptr, n);
    scan_add_kernel<<<(n + 255) / 256, 256, 0, stream>>>(rowptr, boff, cursor, n);
    scatter_kernel<<<(et + 255) / 256, 256, 0, stream>>>(srcA, dstA, cursor, sidx, e, et);

    const int mblocks = (n + 63) / 64;
    const int nodeblocks = (n + 3) / 4;

    // ---- layer 1 ----
    gemm1_kernel<<<mblocks, 256, 0, stream>>>(x, W1, h1h, as1, ad1, al1s, al1d, n);
    agg1_kernel<<<nodeblocks, 256, 0, stream>>>(h1h, sidx, rowptr, al1s, al1d, b1, x2h, n);

    // ---- layer 2 ----
    gemm2_kernel<<<mblocks, 256, 0, stream>>>(x2h, W2, h2h, as2, ad2, al2s, al2d, n, 64, 256);
    agg2_kernel<<<nodeblocks, 256, 0, stream>>>(h2h, sidx, rowptr, al2s, al2d, b2, out, n);
}

// Round 6
// 310.266 us; speedup vs baseline: 3.1925x; 1.0046x over previous
//
#include <hip/hip_runtime.h>
#include <hip/hip_bf16.h>
#include <cstdint>
#include <cstddef>

// ---------------------------------------------------------------------------
// FarmerGAT round 6: parallel edge-dtype detect (was 24us serial); W1/W2
// pre-transposed to fp16 [n][k] so GEMM B-staging is f16x8 vector loads
// (was 32 scalar f32 loads/thread/iter); BK=64 k-loop; hist/scatter read
// edge_index directly (es copy pass deleted); agg1 unrolled 4x (8 rows in
// flight per wave). Softmax fused in aggregation; logits fused in GEMM
// epilogues; fp16 data plane.
// ---------------------------------------------------------------------------

typedef float f32x4 __attribute__((ext_vector_type(4)));
typedef __fp16 f16x8 __attribute__((ext_vector_type(8)));
typedef __fp16 f16x4 __attribute__((ext_vector_type(4)));

static __device__ __forceinline__ float lrelu02(float x) { return x > 0.f ? x : 0.2f * x; }
static __device__ __forceinline__ float eluf(float x)    { return x > 0.f ? x : __expf(x) - 1.f; }

// --- edge dtype detect (parallel): int64 LE with values < 2^31 has zero odd words
__global__ void detect_kernel(const int* __restrict__ ei, int* __restrict__ flag, int e) {
    int lane = threadIdx.x;  // 64
    int m = e < 64 ? e : 64;
    int z = (lane < m && ei[2 * lane + 1] == 0) ? 1 : 0;
    unsigned long long bal = __ballot(z);
    if (lane == 0) *flag = (__popcll(bal) >= m / 2 + 1) ? 1 : 0;
}

// --- dst histogram straight from edge_index
__global__ void hist_kernel(const int* __restrict__ ei, const int* __restrict__ flag,
                            int* __restrict__ deg, int e) {
    int i = blockIdx.x * 256 + threadIdx.x;
    if (i < e) {
        int f = *flag;
        int d = f ? ei[2 * (e + i)] : ei[e + i];
        atomicAdd(&deg[d], 1);
    }
}

// 3-phase scan; each node contributes deg[i]+1 (self-loop)
__global__ __launch_bounds__(256) void scan_blocks_kernel(const int* __restrict__ deg,
                                                          int* __restrict__ loc,
                                                          int* __restrict__ bsum, int n) {
    __shared__ int wsum[4];
    int t = threadIdx.x, lane = t & 63, w = t >> 6;
    int base = blockIdx.x * 1024 + t * 4;
    int4 v = make_int4(0, 0, 0, 0);
    if (base + 3 < n) {
        v = *(const int4*)(deg + base);
        v.x += 1; v.y += 1; v.z += 1; v.w += 1;
    } else {
        if (base < n) v.x = deg[base] + 1;
        if (base + 1 < n) v.y = deg[base + 1] + 1;
        if (base + 2 < n) v.z = deg[base + 2] + 1;
        if (base + 3 < n) v.w = deg[base + 3] + 1;
    }
    int s = v.x + v.y + v.z + v.w;
    int incl = s;
    #pragma unroll
    for (int d = 1; d < 64; d <<= 1) { int o = __shfl_up(incl, d); if (lane >= d) incl += o; }
    if (lane == 63) wsum[w] = incl;
    __syncthreads();
    int woff = 0;
    for (int k = 0; k < w; ++k) woff += wsum[k];
    int excl = woff + incl - s;
    if (base < n) {
        int e0 = excl, e1 = e0 + v.x, e2 = e1 + v.y, e3 = e2 + v.z;
        loc[base] = e0;
        if (base + 1 < n) loc[base + 1] = e1;
        if (base + 2 < n) loc[base + 2] = e2;
        if (base + 3 < n) loc[base + 3] = e3;
    }
    if (t == 255) bsum[blockIdx.x] = woff + incl;
}

__global__ __launch_bounds__(256) void scan_sums_kernel(const int* __restrict__ bsum,
                                                        int* __restrict__ boff, int nb,
                                                        int* __restrict__ rowptr, int n) {
    __shared__ int ws[4];
    int t = threadIdx.x, lane = t & 63, w = t >> 6;
    int v = (t < nb) ? bsum[t] : 0;
    int incl = v;
    #pragma unroll
    for (int d = 1; d < 64; d <<= 1) { int o = __shfl_up(incl, d); if (lane >= d) incl += o; }
    if (lane == 63) ws[w] = incl;
    __syncthreads();
    int woff = 0;
    for (int k = 0; k < w; ++k) woff += ws[k];
    int excl = woff + incl - v;
    if (t < nb) boff[t] = excl;
    if (t == nb - 1) rowptr[n] = excl + v;
}

__global__ void scan_add_kernel(int* __restrict__ rowptr, const int* __restrict__ boff,
                                int* __restrict__ cursor, int n) {
    int i = blockIdx.x * 256 + threadIdx.x;
    if (i < n) {
        int v = rowptr[i] + boff[i >> 10];
        rowptr[i] = v;
        cursor[i] = v;
    }
}

// scatter resolved SOURCE index into CSR position (reads edge_index directly)
__global__ void scatter_kernel(const int* __restrict__ ei, const int* __restrict__ flag,
                               int* __restrict__ cursor, int* __restrict__ sidx,
                               int e, int et) {
    int i = blockIdx.x * 256 + threadIdx.x;
    if (i >= et) return;
    int s, d;
    if (i < e) {
        int f = *flag;
        s = f ? ei[2 * i] : ei[i];
        d = f ? ei[2 * (e + i)] : ei[e + i];
    } else { s = d = i - e; }
    int pos = atomicAdd(&cursor[d], 1);
    sidx[pos] = s;
}

// --- prep: W1 [128][256] f32 -> w1t [256][128] f16; W2 [256][64] f32 -> w2t [64][256] f16
__global__ void prep_kernel(const float* __restrict__ W1, const float* __restrict__ W2,
                            __fp16* __restrict__ w1t, __fp16* __restrict__ w2t) {
    int i = blockIdx.x * 256 + threadIdx.x;  // 49152 total
    if (i < 32768) {
        int nn = i >> 7, k = i & 127;
        w1t[i] = (__fp16)W1[k * 256 + nn];
    } else {
        int j = i - 32768;
        int nn = j >> 8, k = j & 255;
        w2t[j] = (__fp16)W2[k * 64 + nn];
    }
}

// --- GEMM1: C[M,256] f16 = A[M,128] f32 * W1; B pre-transposed fp16 [256][128].
// Block 256 thr = 4 waves; tile 64 rows x full 256 cols; BK=64 (2 iters).
// Fused logits epilogue: thread owns (row, head).
__global__ __launch_bounds__(256) void gemm1_kernel(const float* __restrict__ A,
                                                    const __fp16* __restrict__ w1t,
                                                    __fp16* __restrict__ C,
                                                    const float* __restrict__ a_src,
                                                    const float* __restrict__ a_dst,
                                                    float* __restrict__ als,
                                                    float* __restrict__ ald, int M) {
    __shared__ __fp16 sm[24064];                 // 48128 B
    #define AS(r, c)  sm[(r) * 72 + (c)]        // [64][72]
    #define BST(r, c) sm[4608 + (r) * 72 + (c)] // [256][72] ([n][k])
    #define CS(r, c)  sm[(r) * 264 + (c)]       // [64][264], aliases AS/BST
    float* sa = (float*)(sm + 23040);            // 256 f32
    float* sd = (float*)(sm + 23552);
    int t = threadIdx.x;
    int wv = t >> 6, l = t & 63;
    int lm = l & 15, kq = l >> 4;
    int bm = blockIdx.x * 64;
    sa[t] = a_src[t];
    sd[t] = a_dst[t];
    f32x4 zero = {0.f, 0.f, 0.f, 0.f};
    f32x4 acc[4][4] = {{zero, zero, zero, zero}, {zero, zero, zero, zero},
                       {zero, zero, zero, zero}, {zero, zero, zero, zero}};
    int arow = t >> 2, akp = (t & 3) * 16;
    for (int k0 = 0; k0 < 128; k0 += 64) {
        {   // stage A (f32 -> f16 inline): 16 k per thread
            int gr = bm + arow;
            f16x8 av0, av1;
            if (gr < M) {
                const float* ap = A + (size_t)gr * 128 + k0 + akp;
                float4 a0 = *(const float4*)(ap + 0);
                float4 a1 = *(const float4*)(ap + 4);
                float4 a2 = *(const float4*)(ap + 8);
                float4 a3 = *(const float4*)(ap + 12);
                av0[0] = (__fp16)a0.x; av0[1] = (__fp16)a0.y; av0[2] = (__fp16)a0.z; av0[3] = (__fp16)a0.w;
                av0[4] = (__fp16)a1.x; av0[5] = (__fp16)a1.y; av0[6] = (__fp16)a1.z; av0[7] = (__fp16)a1.w;
                av1[0] = (__fp16)a2.x; av1[1] = (__fp16)a2.y; av1[2] = (__fp16)a2.z; av1[3] = (__fp16)a2.w;
                av1[4] = (__fp16)a3.x; av1[5] = (__fp16)a3.y; av1[6] = (__fp16)a3.z; av1[7] = (__fp16)a3.w;
            } else {
                f16x8 z = {0,0,0,0,0,0,0,0}; av0 = z; av1 = z;
            }
            *(f16x8*)&AS(arow, akp) = av0;
            *(f16x8*)&AS(arow, akp + 8) = av1;
        }
        {   // stage B: n = t, 64 k via 8 vector loads
            const __fp16* bp = w1t + (size_t)t * 128 + k0;
            #pragma unroll
            for (int c = 0; c < 8; ++c)
                *(f16x8*)&BST(t, c * 8) = *(const f16x8*)(bp + c * 8);
        }
        __syncthreads();
        #pragma unroll
        for (int ki = 0; ki < 2; ++ki) {
            int kc = ki * 32 + kq * 8;
            f16x8 af[4];
            #pragma unroll
            for (int mt = 0; mt < 4; ++mt) af[mt] = *(const f16x8*)&AS(mt * 16 + lm, kc);
            #pragma unroll
            for (int nt = 0; nt < 4; ++nt) {
                f16x8 bfrag = *(const f16x8*)&BST(wv * 64 + nt * 16 + lm, kc);
                #pragma unroll
                for (int mt = 0; mt < 4; ++mt)
                    acc[mt][nt] = __builtin_amdgcn_mfma_f32_16x16x32_f16(af[mt], bfrag, acc[mt][nt], 0, 0, 0);
            }
        }
        __syncthreads();
    }
    // transpose C through LDS
    #pragma unroll
    for (int mt = 0; mt < 4; ++mt)
        #pragma unroll
        for (int nt = 0; nt < 4; ++nt)
            #pragma unroll
            for (int r = 0; r < 4; ++r)
                CS(mt * 16 + kq * 4 + r, wv * 64 + nt * 16 + lm) = (__fp16)acc[mt][nt][r];
    __syncthreads();
    {
        int row = t >> 2, head = t & 3;
        int gr = bm + row;
        f16x8 c[8];
        #pragma unroll
        for (int q = 0; q < 8; ++q) c[q] = *(const f16x8*)&CS(row, head * 64 + q * 8);
        float ps = 0.f, pd = 0.f;
        #pragma unroll
        for (int q = 0; q < 8; ++q)
            #pragma unroll
            for (int j = 0; j < 8; ++j) {
                float v = (float)c[q][j];
                ps += v * sa[head * 64 + q * 8 + j];
                pd += v * sd[head * 64 + q * 8 + j];
            }
        if (gr < M) {
            f16x8* gp = (f16x8*)(C + (size_t)gr * 256 + head * 64);
            #pragma unroll
            for (int q = 0; q < 8; ++q) gp[q] = c[q];
            als[gr * 4 + head] = ps;
            ald[gr * 4 + head] = pd;
        }
    }
    #undef AS
    #undef BST
    #undef CS
}

// --- GEMM2: C[M,64] f16 = A[M,256] f16 * W2; B pre-transposed fp16 [64][256].
// Tile 64x64, BK=64 (4 iters). Fused single-head logit epilogue.
__global__ __launch_bounds__(256) void gemm2_kernel(const __fp16* __restrict__ A,
                                                    const __fp16* __restrict__ w2t,
                                                    __fp16* __restrict__ C,
                                                    const float* __restrict__ a_src,
                                                    const float* __restrict__ a_dst,
                                                    float* __restrict__ als,
                                                    float* __restrict__ ald, int M) {
    __shared__ __fp16 sm[9216];                  // 18432 B
    #define AS(r, c)  sm[(r) * 72 + (c)]        // [64][72]
    #define BST(r, c) sm[4608 + (r) * 72 + (c)] // [64][72]
    #define CS(r, c)  sm[(r) * 72 + (c)]        // [64][72], aliases AS
    int t = threadIdx.x;
    int wv = t >> 6, l = t & 63;
    int lm = l & 15, kq = l >> 4;
    int bm = blockIdx.x * 64;
    f32x4 zero = {0.f, 0.f, 0.f, 0.f};
    f32x4 acc[4] = {zero, zero, zero, zero};
    int arow = t >> 2, akp = (t & 3) * 16;
    int bn = t & 63, bkc = (t >> 6) * 16;
    for (int k0 = 0; k0 < 256; k0 += 64) {
        {
            int gr = bm + arow;
            f16x8 av0, av1;
            if (gr < M) {
                const __fp16* ap = A + (size_t)gr * 256 + k0 + akp;
                av0 = *(const f16x8*)(ap);
                av1 = *(const f16x8*)(ap + 8);
            } else { f16x8 z = {0,0,0,0,0,0,0,0}; av0 = z; av1 = z; }
            *(f16x8*)&AS(arow, akp) = av0;
            *(f16x8*)&AS(arow, akp + 8) = av1;
        }
        {
            const __fp16* bp = w2t + (size_t)bn * 256 + k0 + bkc;
            *(f16x8*)&BST(bn, bkc) = *(const f16x8*)(bp);
            *(f16x8*)&BST(bn, bkc + 8) = *(const f16x8*)(bp + 8);
        }
        __syncthreads();
        #pragma unroll
        for (int ki = 0; ki < 2; ++ki) {
            int kc = ki * 32 + kq * 8;
            f16x8 bfrag = *(const f16x8*)&BST(wv * 16 + lm, kc);
            #pragma unroll
            for (int mt = 0; mt < 4; ++mt) {
                f16x8 afrag = *(const f16x8*)&AS(mt * 16 + lm, kc);
                acc[mt] = __builtin_amdgcn_mfma_f32_16x16x32_f16(afrag, bfrag, acc[mt], 0, 0, 0);
            }
        }
        __syncthreads();
    }
    #pragma unroll
    for (int mt = 0; mt < 4; ++mt)
        #pragma unroll
        for (int r = 0; r < 4; ++r)
            CS(mt * 16 + kq * 4 + r, wv * 16 + lm) = (__fp16)acc[mt][r];
    __syncthreads();
    {
        int row = t >> 2, ch = (t & 3) * 16;
        int gr = bm + row;
        f16x8 c0 = *(const f16x8*)&CS(row, ch);
        f16x8 c1 = *(const f16x8*)&CS(row, ch + 8);
        if (gr < M) {
            f16x8* gp = (f16x8*)(C + (size_t)gr * 64 + ch);
            gp[0] = c0; gp[1] = c1;
        }
        float ps = 0.f, pd = 0.f;
        #pragma unroll
        for (int j = 0; j < 8; ++j) {
            float v0 = (float)c0[j], v1 = (float)c1[j];
            ps += v0 * a_src[ch + j] + v1 * a_src[ch + 8 + j];
            pd += v0 * a_dst[ch + j] + v1 * a_dst[ch + 8 + j];
        }
        ps += __shfl_down(ps, 2); ps += __shfl_down(ps, 1);
        pd += __shfl_down(pd, 2); pd += __shfl_down(pd, 1);
        if ((t & 3) == 0 && gr < M) {
            als[gr] = ps;
            ald[gr] = pd;
        }
    }
    #undef AS
    #undef BST
    #undef CS
}

// --- layer1 aggregation, fused softmax: one wave per node, 2 half-wave slots,
// 4x unroll -> 8 rows in flight per wave.
__global__ __launch_bounds__(256) void agg1_kernel(const __fp16* __restrict__ h1,
                                                   const int* __restrict__ sidx,
                                                   const int* __restrict__ rowptr,
                                                   const float* __restrict__ als,
                                                   const float* __restrict__ ald,
                                                   const float* __restrict__ b1,
                                                   __fp16* __restrict__ x2, int n) {
    int t = threadIdx.x, wv = t >> 6, l = t & 63;
    int node = blockIdx.x * 4 + wv;
    if (node >= n) return;
    int le = l & 31, halfE = l >> 5;
    int head = le >> 3;
    float aldn = ald[node * 4 + head];
    int p0 = rowptr[node], p1 = rowptr[node + 1];
    float acc[8] = {0.f, 0.f, 0.f, 0.f, 0.f, 0.f, 0.f, 0.f};
    float accw = 0.f;
    auto body = [&](int p) {
        int s = sidx[p];
        float wt = __expf(lrelu02(als[s * 4 + head] + aldn));
        accw += wt;
        f16x8 r = *(const f16x8*)(h1 + (size_t)s * 256 + le * 8);
        #pragma unroll
        for (int j = 0; j < 8; ++j) acc[j] += wt * (float)r[j];
    };
    int p = p0 + halfE;
    for (; p + 6 < p1; p += 8) { body(p); body(p + 2); body(p + 4); body(p + 6); }
    for (; p < p1; p += 2) body(p);
    #pragma unroll
    for (int j = 0; j < 8; ++j) acc[j] += __shfl_down(acc[j], 32);
    accw += __shfl_down(accw, 32);
    if (l < 32) {
        float rd = 1.f / (accw + 1e-16f);
        f16x8 o;
        #pragma unroll
        for (int j = 0; j < 8; ++j) {
            float v = acc[j] * rd + b1[le * 8 + j];
            o[j] = (__fp16)eluf(v);
        }
        *(f16x8*)(x2 + (size_t)node * 256 + le * 8) = o;
    }
}

// --- layer2 aggregation, fused softmax: one wave per node; 8 slots x 8 lanes.
__global__ __launch_bounds__(256) void agg2_kernel(const __fp16* __restrict__ h2,
                                                   const int* __restrict__ sidx,
                                                   const int* __restrict__ rowptr,
                                                   const float* __restrict__ als,
                                                   const float* __restrict__ ald,
                                                   const float* __restrict__ b2,
                                                   float* __restrict__ out, int n) {
    int t = threadIdx.x, wv = t >> 6, l = t & 63;
    int node = blockIdx.x * 4 + wv;
    if (node >= n) return;
    int slot = l >> 3, cq = l & 7;
    float aldn = ald[node];
    int p0 = rowptr[node], p1 = rowptr[node + 1];
    float acc[8] = {0.f, 0.f, 0.f, 0.f, 0.f, 0.f, 0.f, 0.f};
    float accw = 0.f;
    auto body = [&](int p) {
        int s = sidx[p];
        float wt = __expf(lrelu02(als[s] + aldn));
        accw += wt;
        f16x8 r = *(const f16x8*)(h2 + (size_t)s * 64 + cq * 8);
        #pragma unroll
        for (int j = 0; j < 8; ++j) acc[j] += wt * (float)r[j];
    };
    int p = p0 + slot;
    for (; p + 8 < p1; p += 16) { body(p); body(p + 8); }
    if (p < p1) body(p);
    #pragma unroll
    for (int j = 0; j < 8; ++j) {
        acc[j] += __shfl_down(acc[j], 32);
        acc[j] += __shfl_down(acc[j], 16);
        acc[j] += __shfl_down(acc[j], 8);
    }
    accw += __shfl_down(accw, 32);
    accw += __shfl_down(accw, 16);
    accw += __shfl_down(accw, 8);
    if (l < 8) {
        float rd = 1.f / (accw + 1e-16f);
        float4 o0, o1;
        o0.x = eluf(acc[0] * rd + b2[cq * 8 + 0]);
        o0.y = eluf(acc[1] * rd + b2[cq * 8 + 1]);
        o0.z = eluf(acc[2] * rd + b2[cq * 8 + 2]);
        o0.w = eluf(acc[3] * rd + b2[cq * 8 + 3]);
        o1.x = eluf(acc[4] * rd + b2[cq * 8 + 4]);
        o1.y = eluf(acc[5] * rd + b2[cq * 8 + 5]);
        o1.z = eluf(acc[6] * rd + b2[cq * 8 + 6]);
        o1.w = eluf(acc[7] * rd + b2[cq * 8 + 7]);
        float4* gp = (float4*)(out + (size_t)node * 64 + cq * 8);
        gp[0] = o0; gp[1] = o1;
    }
}

extern "C" void kernel_launch(void* const* d_in, const int* in_sizes, int n_in,
                              void* d_out, int out_size, void* d_ws, size_t ws_size,
                              hipStream_t stream) {
    const float* x   = (const float*)d_in[0];
    const int*   ei  = (const int*)d_in[1];
    const float* W1  = (const float*)d_in[2];
    const float* as1 = (const float*)d_in[3];
    const float* ad1 = (const float*)d_in[4];
    const float* b1  = (const float*)d_in[5];
    const float* W2  = (const float*)d_in[6];
    const float* as2 = (const float*)d_in[7];
    const float* ad2 = (const float*)d_in[8];
    const float* b2  = (const float*)d_in[9];
    float* out = (float*)d_out;

    const int n  = in_sizes[0] / 128;  // 50000
    const int e  = in_sizes[1] / 2;    // 800000
    const int et = e + n;

    char* w = (char*)d_ws;
    size_t off = 0;
    auto take = [&](size_t bytes) -> void* {
        void* p = w + off;
        off = (off + bytes + 255) & ~(size_t)255;
        return p;
    };
    __fp16* h1h = (__fp16*)take((size_t)n * 256 * 2);
    __fp16* x2h = (__fp16*)take((size_t)n * 256 * 2);
    __fp16* h2h = (__fp16*)take((size_t)n * 64 * 2);
    __fp16* w1t = (__fp16*)take((size_t)256 * 128 * 2);
    __fp16* w2t = (__fp16*)take((size_t)64 * 256 * 2);
    float* al1s = (float*)take((size_t)n * 4 * 4);
    float* al1d = (float*)take((size_t)n * 4 * 4);
    float* al2s = (float*)take((size_t)n * 4);
    float* al2d = (float*)take((size_t)n * 4);
    int* deg    = (int*)take((size_t)(n + 1) * 4);
    int* rowptr = (int*)take((size_t)(n + 1) * 4);
    int* cursor = (int*)take((size_t)(n + 1) * 4);
    int* sidx   = (int*)take((size_t)et * 4);
    int* bsum   = (int*)take(1024);
    int* boff   = (int*)take(1024);
    int* flag   = (int*)take(256);

    // edge dtype detect + CSR build
    detect_kernel<<<1, 64, 0, stream>>>(ei, flag, e);
    hipMemsetAsync(deg, 0, (size_t)n * 4, stream);
    prep_kernel<<<192, 256, 0, stream>>>(W1, W2, w1t, w2t);
    hist_kernel<<<(e + 255) / 256, 256, 0, stream>>>(ei, flag, deg, e);
    int nb = (n + 1023) / 1024;
    scan_blocks_kernel<<<nb, 256, 0, stream>>>(deg, rowptr, bsum, n);
    scan_sums_kernel<<<1, 256, 0, stream>>>(bsum, boff, nb, rowptr, n);
    scan_add_kernel<<<(n + 255) / 256, 256, 0, stream>>>(rowptr, boff, cursor, n);
    scatter_kernel<<<(et + 255) / 256, 256, 0, stream>>>(ei, flag, cursor, sidx, e, et);

    const int mblocks = (n + 63) / 64;
    const int nodeblocks = (n + 3) / 4;

    // ---- layer 1 ----
    gemm1_kernel<<<mblocks, 256, 0, stream>>>(x, w1t, h1h, as1, ad1, al1s, al1d, n);
    agg1_kernel<<<nodeblocks, 256, 0, stream>>>(h1h, sidx, rowptr, al1s, al1d, b1, x2h, n);

    // ---- layer 2 ----
    gemm2_kernel<<<mblocks, 256, 0, stream>>>(x2h, w2t, h2h, as2, ad2, al2s, al2d, n);
    agg2_kernel<<<nodeblocks, 256, 0, stream>>>(h2h, sidx, rowptr, al2s, al2d, b2, out, n);
}